// Round 5
// baseline (1256.490 us; speedup 1.0000x reference)
//
#include <hip/hip_runtime.h>
#include <math.h>

typedef __attribute__((ext_vector_type(4))) float f32x4;
typedef __attribute__((ext_vector_type(8))) short s16x8;
typedef __attribute__((ext_vector_type(4))) short s16x4;
typedef unsigned short ushort_t;

#define MFMA16(a, b, c) __builtin_amdgcn_mfma_f32_16x16x32_bf16((a), (b), (c), 0, 0, 0)

// ---------------- workspace byte offsets ----------------
#define WO_CTX    0u          // 32768
#define WO_HDN    32768u      // 2048
#define WO_BNSUM  34816u      // 1024
#define WO_BNSQ   35840u      // 1024
#define WO_SCALE  36864u      // 1024
#define WO_SHIFT  37888u      // 1024
#define WO_COEF   40960u      // 4194304
#define WO_BMT_H  4235264u    // 8192  (64x64 bf16)
#define WO_BMT_L  4243456u
#define WO_FARE_H 4251648u    // 16384 (64x128)
#define WO_FARE_L 4268032u
#define WO_FAIM_H 4284416u
#define WO_FAIM_L 4300800u
#define WO_FDRE_H 4317184u
#define WO_FDRE_L 4333568u
#define WO_FDIM_H 4349952u
#define WO_FDIM_L 4366336u
#define WO_DTT_H  4382720u    // 8192 (64x64)
#define WO_DTT_L  4390912u
#define WO_CW_H   4399104u    // 131072 (256x256)
#define WO_CW_L   4530176u
#define WO_YBF    4661248u    // 51380224 (8192*3136 bf16)
#define WO_BASRT  56041472u   // 57344 (1792x8 fp32, [q][k])
#define WO_BASIT  56098816u   // 57344

__device__ __forceinline__ ushort_t f2bf(float f) {
  unsigned int u = __builtin_bit_cast(unsigned int, f);
  unsigned int r = (u + 0x7fffu + ((u >> 16) & 1u)) >> 16;
  return (ushort_t)r;
}
__device__ __forceinline__ float bf2f(ushort_t h) {
  unsigned int u = ((unsigned int)h) << 16;
  return __builtin_bit_cast(float, u);
}

// ---------------- constant-matrix math (double precision) ----------------
__device__ double bmat_val(int w, int vv) {
  // column vv of (resize56->62 then rfft62, fwd ortho): vv<32 Re, else Im
  const int v = vv & 31;
  const bool isI = vv >= 32;
  double accR = 0.0, accI = 0.0;
  for (int wp = 0; wp < 62; ++wp) {
    const double src = (wp + 0.5) * (56.0 / 62.0) - 0.5;
    const int w0 = (int)floor(src);
    const double f = src - (double)w0;
    const double s0 = (w0 >= 0 && w0 <= 55) ? (1.0 - f) : 0.0;
    const double s1 = (w0 + 1 >= 0 && w0 + 1 <= 55) ? f : 0.0;
    const double ssum = s0 + s1;
    double wgt = 0.0;
    if (w == w0) wgt = s0 / ssum;
    else if (w == w0 + 1) wgt = s1 / ssum;
    if (wgt != 0.0) {
      const int p = (v * wp) % 62;
      const double ang = 6.283185307179586476925286766559 * (double)p / 62.0;
      accR += wgt * cos(ang);
      accI -= wgt * sin(ang);
    }
  }
  const double nrm = 1.0 / sqrt(3472.0);
  return (isI ? accI : accR) * nrm;
}

// DtStack component: v in [0,32), isI selects Im; wq = output column 0..55.
__device__ double dt_component(int v, bool isI, int wq) {
  const double ks = 62.0 / 56.0;
  const double src = (wq + 0.5) * ks - 0.5;
  double wsum = 0.0;
  for (int wp = 0; wp < 62; ++wp) {
    const double xx = fabs(src - (double)wp) / ks;
    if (xx < 1.0) wsum += 1.0 - xx;
  }
  const double cv = (v == 0 || v == 31) ? 1.0 : 2.0;
  double accR = 0.0, accI = 0.0;
  for (int wp = 0; wp < 62; ++wp) {
    const double xx = fabs(src - (double)wp) / ks;
    if (xx >= 1.0) continue;
    const double wgt = (1.0 - xx) / wsum;
    double cc, ss;
    if (v == 0)       { cc = 1.0; ss = 0.0; }
    else if (v == 31) { cc = (wp & 1) ? -1.0 : 1.0; ss = 0.0; }
    else {
      const int p = (v * wp) % 62;
      const double ang = 6.283185307179586476925286766559 * (double)p / 62.0;
      cc = cos(ang); ss = sin(ang);
    }
    accR += wgt * cv * cc;
    accI -= wgt * cv * ss;
  }
  const double nrm = 1.0 / sqrt(3472.0);
  return (isI ? accI : accR) * nrm;
}

__device__ __forceinline__ void emit_hilo(ushort_t* hp, ushort_t* lp, int off, double val) {
  const float fv = (float)val;
  const ushort_t h = f2bf(fv);
  const float hf = bf2f(h);
  const ushort_t l = f2bf((float)(val - (double)hf));
  hp[off] = h;
  lp[off] = l;
}

__global__ void k_const(const float* __restrict__ conv_w,
                        const float* __restrict__ basR, const float* __restrict__ basI,
                        ushort_t* BmT_h, ushort_t* BmT_l,
                        ushort_t* FARe_h, ushort_t* FARe_l,
                        ushort_t* FAIm_h, ushort_t* FAIm_l,
                        ushort_t* FDRe_h, ushort_t* FDRe_l,
                        ushort_t* FDIm_h, ushort_t* FDIm_l,
                        ushort_t* DtT_h, ushort_t* DtT_l,
                        ushort_t* W_h, ushort_t* W_l,
                        float* basRT, float* basIT) {
  const int idx = blockIdx.x * 256 + threadIdx.x;
  if (idx < 4096) {
    // BmT[vv][k=w], k>=56 zero
    const int vv = idx >> 6, k = idx & 63;
    const double v = (k < 56) ? bmat_val(k, vv) : 0.0;
    emit_hilo(BmT_h, BmT_l, idx, v);
  } else if (idx < 36864) {
    const int t = (idx - 4096) & 8191;
    const int which = (idx - 4096) >> 13;  // 0 FARe, 1 FAIm, 2 FDRe, 3 FDIm
    const int row = t >> 7, k = t & 127;
    double val = 0.0;
    if (row < 56 && k < 112) {
      const int h = (k < 56) ? k : k - 56;
      const double ang = 6.283185307179586476925286766559 *
                         (double)((row * h) % 56) / 56.0;
      const double c = cos(ang), s = sin(ang);
      const bool lowk = (k < 56);
      // fwd: e^{-i t} -> Re=[c|s], Im=[-s|c]; inv: e^{+i t} -> Re=[c|-s], Im=[s|c]
      if (which == 0)      val = lowk ? c : s;
      else if (which == 1) val = lowk ? -s : c;
      else if (which == 2) val = lowk ? c : -s;
      else                 val = lowk ? s : c;
    }
    ushort_t* hp = (which == 0) ? FARe_h : (which == 1) ? FAIm_h : (which == 2) ? FDRe_h : FDIm_h;
    ushort_t* lp = (which == 0) ? FARe_l : (which == 1) ? FAIm_l : (which == 2) ? FDRe_l : FDIm_l;
    emit_hilo(hp, lp, t, val);
  } else if (idx < 40960) {
    // DtT rows INTERLEAVED to match ta layout: kk = 2*v + isIm
    const int t = idx - 36864;
    const int w = t >> 6, kk = t & 63;
    const double val = (w < 56) ? dt_component(kk >> 1, (kk & 1) != 0, w) : 0.0;
    emit_hilo(DtT_h, DtT_l, t, val);
  } else if (idx < 106496) {
    const int t = idx - 40960;
    emit_hilo(W_h, W_l, t, (double)conv_w[t]);
  } else if (idx < 135168) {
    // transposed basis: basRT/basIT[q*8+k] = bas{R,I}[k*1792+q]
    const int t = idx - 106496;         // 0..28671
    const int tt = t - (t / 14336) * 14336;
    const int m2 = t / 14336;
    const int q = tt >> 3, k = tt & 7;
    if (m2 == 0) basRT[tt] = basR[k * 1792 + q];
    else         basIT[tt] = basI[k * 1792 + q];
  }
}

// ---------------- GAP ----------------
__global__ __launch_bounds__(256) void k_gap(const float* __restrict__ x,
                                             float* __restrict__ ctx) {
  const int img = blockIdx.x;
  const int tid = threadIdx.x;
  const float4* p4 = (const float4*)(x + (size_t)img * 3136);
  float s = 0.f;
  for (int i = tid; i < 784; i += 256) {
    const float4 v = p4[i];
    s += v.x + v.y + v.z + v.w;
  }
  for (int off = 32; off > 0; off >>= 1) s += __shfl_down(s, off, 64);
  __shared__ float ls[4];
  if ((tid & 63) == 0) ls[tid >> 6] = s;
  __syncthreads();
  if (tid == 0) ctx[img] = (ls[0] + ls[1] + ls[2] + ls[3]) * (1.0f / 3136.0f);
}

// ---------------- fc1 + LN + ReLU ----------------
__global__ void k_mlp(const float* __restrict__ ctx, const float* __restrict__ fc1_w,
                      const float* __restrict__ fc1_b, const float* __restrict__ ln_g,
                      const float* __restrict__ ln_b, float* __restrict__ hdn) {
  const int b = blockIdx.x;
  const int j = threadIdx.x;
  __shared__ float h[16];
  if (j < 16) {
    const float* cr = ctx + b * 256;
    const float* wr = fc1_w + j * 256;
    float acc = fc1_b[j];
    for (int c0 = 0; c0 < 256; ++c0) acc = fmaf(cr[c0], wr[c0], acc);
    h[j] = acc;
  }
  __syncthreads();
  if (j < 16) {
    float mu = 0.f, m2 = 0.f;
    for (int t = 0; t < 16; ++t) { mu += h[t]; m2 += h[t] * h[t]; }
    mu *= 0.0625f; m2 *= 0.0625f;
    const float var = m2 - mu * mu;
    const float val = (h[j] - mu) / sqrtf(var + 1e-5f) * ln_g[j] + ln_b[j];
    hdn[b * 16 + j] = fmaxf(val, 0.f);
  }
}

// ---------------- fourier head + softmax ----------------
__global__ __launch_bounds__(256) void k_coeffs(const float* __restrict__ hdn,
                                                const float* __restrict__ fh_w,
                                                const float* __restrict__ fh_b,
                                                float* __restrict__ coeffs) {
  const int gid = blockIdx.x * 256 + threadIdx.x;
  const int b = gid >> 12;
  const int cm = gid & 4095;
  float hv[16];
  const float* hp = hdn + b * 16;
#pragma unroll
  for (int j = 0; j < 16; ++j) hv[j] = hp[j];
  const int row0 = cm * 8;
  float a[8];
  float mx = -1e30f;
#pragma unroll
  for (int k = 0; k < 8; ++k) {
    const float* wr = fh_w + (size_t)(row0 + k) * 16;
    float acc = fh_b[row0 + k];
#pragma unroll
    for (int j = 0; j < 16; ++j) acc = fmaf(hv[j], wr[j], acc);
    a[k] = acc;
    mx = fmaxf(mx, acc);
  }
  float s = 0.f;
#pragma unroll
  for (int k = 0; k < 8; ++k) { a[k] = expf(a[k] - mx); s += a[k]; }
  const float inv = 1.f / s;
  float* outp = coeffs + (size_t)gid * 8;
#pragma unroll
  for (int k = 0; k < 8; ++k) outp[k] = a[k] * inv;
}

// ---------------- fused spectral branch: ONE WAVE per image, ONE LDS region ----
// 64-thread blocks, 9216 B LDS. The single region serves, in sequence:
//   x [64][72] -> x1T [32][136] -> x2T [32][136] -> ta [64][72]
// Each stage's output is held PACKED IN REGISTERS (~32 VGPRs, fully static
// indexing) until the input is dead, then written in place. x1T's zeroed K-pad
// (cols 112..127) persists under x2T (x2T writes only cols 0..111), so it is
// zeroed once. __launch_bounds__(64,4) targets 4 waves/SIMD = 16 blocks/CU.
__global__ __launch_bounds__(64, 4) void k_fft(
    const float* __restrict__ x, const float* __restrict__ coeffs,
    const float* __restrict__ basRT, const float* __restrict__ basIT,
    const ushort_t* __restrict__ BmT_h, const ushort_t* __restrict__ BmT_l,
    const ushort_t* __restrict__ FARe_h, const ushort_t* __restrict__ FARe_l,
    const ushort_t* __restrict__ FAIm_h, const ushort_t* __restrict__ FAIm_l,
    const ushort_t* __restrict__ FDRe_h, const ushort_t* __restrict__ FDRe_l,
    const ushort_t* __restrict__ FDIm_h, const ushort_t* __restrict__ FDIm_l,
    const ushort_t* __restrict__ DtT_h, const ushort_t* __restrict__ DtT_l,
    ushort_t* __restrict__ ybf) {
  __shared__ __align__(16) ushort_t reg[4608];   // 9216 B
  const int img = blockIdx.x;
  const int lane = threadIdx.x;                  // 0..63
  const int col = lane & 15, quad = lane >> 4;
  const f32x4 zf = {0.f, 0.f, 0.f, 0.f};

  // ---- phase 1: zero x K-pads (rows<56, cols 56..63); load x -> reg ----
  {
#pragma unroll
    for (int i = 0; i < 4; ++i) {
      const int t = i * 64 + lane;
      if (t < 224) {
        const int h = t >> 2, c = t & 3;
        *(unsigned int*)&reg[h * 72 + 56 + c * 2] = 0u;
      }
    }
    const float4* xp = (const float4*)(x + (size_t)img * 3136);
    for (int f = lane; f < 784; f += 64) {
      const float4 v = xp[f];
      const int h = f / 14, w4 = (f % 14) * 4;
      s16x4 p;
      p[0] = (short)f2bf(v.x); p[1] = (short)f2bf(v.y);
      p[2] = (short)f2bf(v.z); p[3] = (short)f2bf(v.w);
      *(s16x4*)&reg[h * 72 + w4] = p;
    }
  }
  __syncthreads();

  // stage b: x1 = x @ Bmat; outputs held in hb, then reg overwritten as x1T
  {
    s16x4 hb[4][4];
#pragma unroll
    for (int mt = 0; mt < 4; ++mt) {
      const int arow = (mt * 16 + col) * 72;
      const s16x8 a0 = *(const s16x8*)&reg[arow + quad * 8];
      const s16x8 a1 = *(const s16x8*)&reg[arow + 32 + quad * 8];
#pragma unroll
      for (int nt = 0; nt < 4; ++nt) {
        const int nrow = nt * 16 + col;  // vv
        const s16x8 bh0 = *(const s16x8*)&BmT_h[nrow * 64 + quad * 8];
        const s16x8 bl0 = *(const s16x8*)&BmT_l[nrow * 64 + quad * 8];
        const s16x8 bh1 = *(const s16x8*)&BmT_h[nrow * 64 + 32 + quad * 8];
        const s16x8 bl1 = *(const s16x8*)&BmT_l[nrow * 64 + 32 + quad * 8];
        f32x4 acc = zf;
        acc = MFMA16(a0, bh0, acc);
        acc = MFMA16(a0, bl0, acc);
        acc = MFMA16(a1, bh1, acc);
        acc = MFMA16(a1, bl1, acc);
        s16x4 p;
        p[0] = (short)f2bf(acc[0]); p[1] = (short)f2bf(acc[1]);
        p[2] = (short)f2bf(acc[2]); p[3] = (short)f2bf(acc[3]);
        hb[mt][nt] = p;
      }
    }
    __syncthreads();   // all x reads done; reg may be overwritten
    // zero x1T K-pad: rows 0..31, cols 112..127 (persists under x2T too)
#pragma unroll
    for (int i = 0; i < 4; ++i) {
      const int t = i * 64 + lane;
      const int r = t >> 3, c = t & 7;
      *(unsigned int*)&reg[r * 136 + 112 + c * 2] = 0u;
    }
#pragma unroll
    for (int mt = 0; mt < 4; ++mt) {
      const int h0 = mt * 16 + quad * 4;
      if (h0 < 56) {
#pragma unroll
        for (int nt = 0; nt < 4; ++nt) {
          const int vr = (nt & 1) * 16 + col;
          const int kk = h0 + ((nt >= 2) ? 56 : 0);
          *(s16x4*)&reg[vr * 136 + kk] = hb[mt][nt];
        }
      }
    }
  }
  __syncthreads();

  // stage c: X2 = Fh_fwd @ x1, filter by inline-G; held in hcR/hcI -> reg as x2T
  {
    const float* co = coeffs + (size_t)img * 128;
    s16x4 hcR[4][2], hcI[4][2];
#pragma unroll
    for (int mt = 0; mt < 4; ++mt) {
      f32x4 accRe[2] = {zf, zf}, accIm[2] = {zf, zf};
#pragma unroll
      for (int ks = 0; ks < 4; ++ks) {
        const int aoff = (mt * 16 + col) * 128 + ks * 32 + quad * 8;
        const s16x8 aRh = *(const s16x8*)&FARe_h[aoff];
        const s16x8 aRl = *(const s16x8*)&FARe_l[aoff];
        const s16x8 aIh = *(const s16x8*)&FAIm_h[aoff];
        const s16x8 aIl = *(const s16x8*)&FAIm_l[aoff];
#pragma unroll
        for (int nt = 0; nt < 2; ++nt) {
          const s16x8 b = *(const s16x8*)&reg[(nt * 16 + col) * 136 + ks * 32 + quad * 8];
          accRe[nt] = MFMA16(aRh, b, accRe[nt]);
          accRe[nt] = MFMA16(aRl, b, accRe[nt]);
          accIm[nt] = MFMA16(aIh, b, accIm[nt]);
          accIm[nt] = MFMA16(aIl, b, accIm[nt]);
        }
      }
      const int u0 = mt * 16 + quad * 4;
#pragma unroll
      for (int nt = 0; nt < 2; ++nt) {
        const int v = nt * 16 + col;
        s16x4 pR, pI;
#pragma unroll
        for (int r = 0; r < 4; ++r) {
          const int u = u0 + r;
          const int q = u * 32 + v;
          const int m = (u / 14) * 4 + (v >> 3);
          const float4 c0 = *(const float4*)&co[m * 8];
          const float4 c1 = *(const float4*)&co[m * 8 + 4];
          const float4 br0 = *(const float4*)&basRT[q * 8];
          const float4 br1 = *(const float4*)&basRT[q * 8 + 4];
          const float4 bi0 = *(const float4*)&basIT[q * 8];
          const float4 bi1 = *(const float4*)&basIT[q * 8 + 4];
          float gr = 0.f, gi = 0.f;
          gr = fmaf(c0.x, br0.x, gr); gi = fmaf(c0.x, bi0.x, gi);
          gr = fmaf(c0.y, br0.y, gr); gi = fmaf(c0.y, bi0.y, gi);
          gr = fmaf(c0.z, br0.z, gr); gi = fmaf(c0.z, bi0.z, gi);
          gr = fmaf(c0.w, br0.w, gr); gi = fmaf(c0.w, bi0.w, gi);
          gr = fmaf(c1.x, br1.x, gr); gi = fmaf(c1.x, bi1.x, gi);
          gr = fmaf(c1.y, br1.y, gr); gi = fmaf(c1.y, bi1.y, gi);
          gr = fmaf(c1.z, br1.z, gr); gi = fmaf(c1.z, bi1.z, gi);
          gr = fmaf(c1.w, br1.w, gr); gi = fmaf(c1.w, bi1.w, gi);
          const float re = accRe[nt][r] * gr - accIm[nt][r] * gi;
          const float im = accRe[nt][r] * gi + accIm[nt][r] * gr;
          pR[r] = (short)f2bf(re);
          pI[r] = (short)f2bf(im);
        }
        hcR[mt][nt] = pR;
        hcI[mt][nt] = pI;
      }
    }
    __syncthreads();   // all x1T reads done
#pragma unroll
    for (int mt = 0; mt < 4; ++mt) {
      const int u0 = mt * 16 + quad * 4;
      if (u0 < 56) {
#pragma unroll
        for (int nt = 0; nt < 2; ++nt) {
          const int v = nt * 16 + col;
          *(s16x4*)&reg[v * 136 + u0] = hcR[mt][nt];
          *(s16x4*)&reg[v * 136 + 56 + u0] = hcI[mt][nt];
        }
      }
    }
  }
  __syncthreads();

  // stage d: T = Fh_inv @ X2f; held packed u32 -> reg as ta [h][2v Re,Im]
  {
    unsigned int hd[4][2][4];
#pragma unroll
    for (int mt = 0; mt < 4; ++mt) {
      f32x4 accRe[2] = {zf, zf}, accIm[2] = {zf, zf};
#pragma unroll
      for (int ks = 0; ks < 4; ++ks) {
        const int aoff = (mt * 16 + col) * 128 + ks * 32 + quad * 8;
        const s16x8 aRh = *(const s16x8*)&FDRe_h[aoff];
        const s16x8 aRl = *(const s16x8*)&FDRe_l[aoff];
        const s16x8 aIh = *(const s16x8*)&FDIm_h[aoff];
        const s16x8 aIl = *(const s16x8*)&FDIm_l[aoff];
#pragma unroll
        for (int nt = 0; nt < 2; ++nt) {
          const s16x8 b = *(const s16x8*)&reg[(nt * 16 + col) * 136 + ks * 32 + quad * 8];
          accRe[nt] = MFMA16(aRh, b, accRe[nt]);
          accRe[nt] = MFMA16(aRl, b, accRe[nt]);
          accIm[nt] = MFMA16(aIh, b, accIm[nt]);
          accIm[nt] = MFMA16(aIl, b, accIm[nt]);
        }
      }
#pragma unroll
      for (int nt = 0; nt < 2; ++nt) {
#pragma unroll
        for (int r = 0; r < 4; ++r) {
          hd[mt][nt][r] = (unsigned int)f2bf(accRe[nt][r]) |
                          ((unsigned int)f2bf(accIm[nt][r]) << 16);
        }
      }
    }
    __syncthreads();   // all x2T reads done
#pragma unroll
    for (int mt = 0; mt < 4; ++mt) {
      const int h0 = mt * 16 + quad * 4;
#pragma unroll
      for (int nt = 0; nt < 2; ++nt) {
        const int v = nt * 16 + col;
#pragma unroll
        for (int r = 0; r < 4; ++r) {
          *(unsigned int*)&reg[(h0 + r) * 72 + 2 * v] = hd[mt][nt][r];
        }
      }
    }
  }
  __syncthreads();

  // stage e: y = T @ DtStack (K=64, rows interleaved to match ta), store bf16
  {
    ushort_t* yo = ybf + (size_t)img * 3136;
#pragma unroll
    for (int mt = 0; mt < 4; ++mt) {
      const int arow = (mt * 16 + col) * 72;
      const s16x8 a0 = *(const s16x8*)&reg[arow + quad * 8];
      const s16x8 a1 = *(const s16x8*)&reg[arow + 32 + quad * 8];
      const int h0 = mt * 16 + quad * 4;
#pragma unroll
      for (int nt = 0; nt < 4; ++nt) {
        const int w = nt * 16 + col;
        const s16x8 bh0 = *(const s16x8*)&DtT_h[w * 64 + quad * 8];
        const s16x8 bl0 = *(const s16x8*)&DtT_l[w * 64 + quad * 8];
        const s16x8 bh1 = *(const s16x8*)&DtT_h[w * 64 + 32 + quad * 8];
        const s16x8 bl1 = *(const s16x8*)&DtT_l[w * 64 + 32 + quad * 8];
        f32x4 acc = zf;
        acc = MFMA16(a0, bh0, acc);
        acc = MFMA16(a0, bl0, acc);
        acc = MFMA16(a1, bh1, acc);
        acc = MFMA16(a1, bl1, acc);
        if (h0 < 56 && w < 56) {
#pragma unroll
          for (int r = 0; r < 4; ++r) yo[(h0 + r) * 56 + w] = f2bf(acc[r]);
        }
      }
    }
  }
}

// ---------------- 1x1 conv via MFMA: A=W(hi/lo), B=y bf16 direct from global ----------------
__global__ __launch_bounds__(256) void k_conv(const ushort_t* __restrict__ ybf,
                                              const ushort_t* __restrict__ W_h,
                                              const ushort_t* __restrict__ W_l,
                                              float* __restrict__ z) {
  const int pb = blockIdx.x;   // 0..12, 256 pixels each (last ragged)
  const int oh = blockIdx.y;   // 0..1, 128 out-channels each
  const int b = blockIdx.z;
  const int tid = threadIdx.x;
  const int wave = tid >> 6, lane = tid & 63, col = lane & 15, quad = lane >> 4;
  const f32x4 zf = {0.f, 0.f, 0.f, 0.f};
  f32x4 acc[8][4];
#pragma unroll
  for (int mt = 0; mt < 8; ++mt)
#pragma unroll
    for (int i = 0; i < 4; ++i) acc[mt][i] = zf;

  const size_t ybase = (size_t)b * 256 * 3136;
  int p0i[4];
  bool act[4];
#pragma unroll
  for (int i = 0; i < 4; ++i) {
    p0i[i] = pb * 256 + (wave * 4 + i) * 16;
    act[i] = p0i[i] < 3136;
  }

  for (int ks = 0; ks < 8; ++ks) {
    const int c0 = ks * 32 + quad * 8;
    s16x8 bfr[4];
#pragma unroll
    for (int i = 0; i < 4; ++i) {
      if (act[i]) {
        s16x8 t;
#pragma unroll
        for (int j = 0; j < 8; ++j)
          t[j] = (short)ybf[ybase + (size_t)(c0 + j) * 3136 + p0i[i] + col];
        bfr[i] = t;
      }
    }
#pragma unroll
    for (int mt = 0; mt < 8; ++mt) {
      const int orow = oh * 128 + mt * 16 + col;
      const s16x8 ah = *(const s16x8*)&W_h[orow * 256 + ks * 32 + quad * 8];
      const s16x8 al = *(const s16x8*)&W_l[orow * 256 + ks * 32 + quad * 8];
#pragma unroll
      for (int i = 0; i < 4; ++i) {
        if (act[i]) {
          acc[mt][i] = MFMA16(ah, bfr[i], acc[mt][i]);
          acc[mt][i] = MFMA16(al, bfr[i], acc[mt][i]);
        }
      }
    }
  }

#pragma unroll
  for (int mt = 0; mt < 8; ++mt) {
#pragma unroll
    for (int i = 0; i < 4; ++i) {
      if (!act[i]) continue;
#pragma unroll
      for (int r = 0; r < 4; ++r) {
        const int o = oh * 128 + mt * 16 + quad * 4 + r;
        z[((size_t)b * 256 + o) * 3136 + p0i[i] + col] = acc[mt][i][r];
      }
    }
  }
}

// ---------------- BN sums over z ----------------
__global__ __launch_bounds__(256) void k_bnsum(const float* __restrict__ z,
                                               float* __restrict__ bnsum,
                                               float* __restrict__ bnsq) {
  const int bo = blockIdx.x;  // b*256+o
  const int tid = threadIdx.x;
  const float4* p4 = (const float4*)(z + (size_t)bo * 3136);
  float s = 0.f, s2 = 0.f;
  for (int i = tid; i < 784; i += 256) {
    const float4 v = p4[i];
    s += v.x + v.y + v.z + v.w;
    s2 += v.x * v.x + v.y * v.y + v.z * v.z + v.w * v.w;
  }
  for (int off = 32; off > 0; off >>= 1) {
    s += __shfl_down(s, off, 64);
    s2 += __shfl_down(s2, off, 64);
  }
  __shared__ float ls[8];
  if ((tid & 63) == 0) { ls[tid >> 6] = s; ls[4 + (tid >> 6)] = s2; }
  __syncthreads();
  if (tid == 0) {
    atomicAdd(bnsum + (bo & 255), ls[0] + ls[1] + ls[2] + ls[3]);
    atomicAdd(bnsq + (bo & 255), ls[4] + ls[5] + ls[6] + ls[7]);
  }
}

__global__ void k_bnstats(const float* __restrict__ bnsum, const float* __restrict__ bnsq,
                          const float* __restrict__ bn_g, const float* __restrict__ bn_b,
                          float* __restrict__ scale, float* __restrict__ shift) {
  const int o = threadIdx.x;
  if (o < 256) {
    const float N = 32.f * 3136.f;
    const float m = bnsum[o] / N;
    const float v = bnsq[o] / N - m * m;
    const float sc = bn_g[o] / sqrtf(v + 1e-5f);
    scale[o] = sc;
    shift[o] = bn_b[o] - m * sc;
  }
}

__global__ __launch_bounds__(256) void k_bnapply(float* __restrict__ z,
                                                 const float* __restrict__ scale,
                                                 const float* __restrict__ shift) {
  const size_t i = ((size_t)blockIdx.x * 256 + threadIdx.x) * 4;
  const int ch = (int)((i / 3136) & 255);
  const float sc = scale[ch], sh = shift[ch];
  float4 v = *(float4*)(z + i);
  v.x = fmaf(v.x, sc, sh);
  v.y = fmaf(v.y, sc, sh);
  v.z = fmaf(v.z, sc, sh);
  v.w = fmaf(v.w, sc, sh);
  *(float4*)(z + i) = v;
}

extern "C" void kernel_launch(void* const* d_in, const int* in_sizes, int n_in,
                              void* d_out, int out_size, void* d_ws, size_t ws_size,
                              hipStream_t stream) {
  const float* x          = (const float*)d_in[0];
  const float* fc1_w      = (const float*)d_in[1];
  const float* fc1_b      = (const float*)d_in[2];
  const float* ln_g       = (const float*)d_in[3];
  const float* ln_b       = (const float*)d_in[4];
  const float* fh_w       = (const float*)d_in[5];
  const float* fh_b       = (const float*)d_in[6];
  const float* basis_real = (const float*)d_in[7];
  const float* basis_imag = (const float*)d_in[8];
  const float* conv_w     = (const float*)d_in[9];
  const float* bn_g       = (const float*)d_in[10];
  const float* bn_b       = (const float*)d_in[11];
  float* out = (float*)d_out;
  char* ws = (char*)d_ws;
  (void)in_sizes; (void)n_in; (void)out_size; (void)ws_size;

  float* ctx   = (float*)(ws + WO_CTX);
  float* hdn   = (float*)(ws + WO_HDN);
  float* bnsum = (float*)(ws + WO_BNSUM);
  float* bnsq  = (float*)(ws + WO_BNSQ);
  float* scale = (float*)(ws + WO_SCALE);
  float* shift = (float*)(ws + WO_SHIFT);
  float* coef  = (float*)(ws + WO_COEF);
  ushort_t* BmT_h  = (ushort_t*)(ws + WO_BMT_H);
  ushort_t* BmT_l  = (ushort_t*)(ws + WO_BMT_L);
  ushort_t* FARe_h = (ushort_t*)(ws + WO_FARE_H);
  ushort_t* FARe_l = (ushort_t*)(ws + WO_FARE_L);
  ushort_t* FAIm_h = (ushort_t*)(ws + WO_FAIM_H);
  ushort_t* FAIm_l = (ushort_t*)(ws + WO_FAIM_L);
  ushort_t* FDRe_h = (ushort_t*)(ws + WO_FDRE_H);
  ushort_t* FDRe_l = (ushort_t*)(ws + WO_FDRE_L);
  ushort_t* FDIm_h = (ushort_t*)(ws + WO_FDIM_H);
  ushort_t* FDIm_l = (ushort_t*)(ws + WO_FDIM_L);
  ushort_t* DtT_h  = (ushort_t*)(ws + WO_DTT_H);
  ushort_t* DtT_l  = (ushort_t*)(ws + WO_DTT_L);
  ushort_t* W_h    = (ushort_t*)(ws + WO_CW_H);
  ushort_t* W_l    = (ushort_t*)(ws + WO_CW_L);
  ushort_t* ybf    = (ushort_t*)(ws + WO_YBF);
  float* basRT = (float*)(ws + WO_BASRT);
  float* basIT = (float*)(ws + WO_BASIT);

  hipMemsetAsync(bnsum, 0, 2048, stream);  // bnsum+bnsq contiguous

  hipLaunchKernelGGL(k_const, dim3(528), dim3(256), 0, stream,
                     conv_w, basis_real, basis_imag,
                     BmT_h, BmT_l, FARe_h, FARe_l, FAIm_h, FAIm_l,
                     FDRe_h, FDRe_l, FDIm_h, FDIm_l, DtT_h, DtT_l, W_h, W_l,
                     basRT, basIT);
  hipLaunchKernelGGL(k_gap, dim3(8192), dim3(256), 0, stream, x, ctx);
  hipLaunchKernelGGL(k_mlp, dim3(32), dim3(64), 0, stream,
                     ctx, fc1_w, fc1_b, ln_g, ln_b, hdn);
  hipLaunchKernelGGL(k_coeffs, dim3(512), dim3(256), 0, stream, hdn, fh_w, fh_b, coef);
  hipLaunchKernelGGL(k_fft, dim3(8192), dim3(64), 0, stream,
                     x, coef, basRT, basIT,
                     BmT_h, BmT_l, FARe_h, FARe_l, FAIm_h, FAIm_l,
                     FDRe_h, FDRe_l, FDIm_h, FDIm_l, DtT_h, DtT_l, ybf);
  hipLaunchKernelGGL(k_conv, dim3(13, 2, 32), dim3(256), 0, stream, ybf, W_h, W_l, out);
  hipLaunchKernelGGL(k_bnsum, dim3(8192), dim3(256), 0, stream, out, bnsum, bnsq);
  hipLaunchKernelGGL(k_bnstats, dim3(1), dim3(256), 0, stream,
                     bnsum, bnsq, bn_g, bn_b, scale, shift);
  hipLaunchKernelGGL(k_bnapply, dim3(25088), dim3(256), 0, stream, out, scale, shift);
}

// Round 6
// 881.177 us; speedup vs baseline: 1.4259x; 1.4259x over previous
//
#include <hip/hip_runtime.h>
#include <math.h>

typedef __attribute__((ext_vector_type(4))) float f32x4;
typedef __attribute__((ext_vector_type(8))) short s16x8;
typedef __attribute__((ext_vector_type(4))) short s16x4;
typedef unsigned short ushort_t;

#define MFMA16(a, b, c) __builtin_amdgcn_mfma_f32_16x16x32_bf16((a), (b), (c), 0, 0, 0)

// ---------------- workspace byte offsets ----------------
#define WO_CTX    0u          // 32768
#define WO_HDN    32768u      // 2048
#define WO_BNSUM  34816u      // 1024
#define WO_BNSQ   35840u      // 1024
#define WO_SCALE  36864u      // 1024
#define WO_SHIFT  37888u      // 1024
#define WO_COEF   40960u      // 4194304
#define WO_BMT_H  4235264u    // 8192  (64x64 bf16)
#define WO_BMT_L  4243456u
#define WO_FARE_H 4251648u    // 16384 (64x128)
#define WO_FARE_L 4268032u
#define WO_FAIM_H 4284416u
#define WO_FAIM_L 4300800u
#define WO_FDRE_H 4317184u
#define WO_FDRE_L 4333568u
#define WO_FDIM_H 4349952u
#define WO_FDIM_L 4366336u
#define WO_DTT_H  4382720u    // 8192 (64x64)
#define WO_DTT_L  4390912u
#define WO_CW_H   4399104u    // 131072 (256x256)
#define WO_CW_L   4530176u
#define WO_YBF    4661248u    // 51380224 (8192*3136 bf16)
#define WO_BASRT  56041472u   // 57344 (1792x8 fp32, [q][k])
#define WO_BASIT  56098816u   // 57344

__device__ __forceinline__ ushort_t f2bf(float f) {
  unsigned int u = __builtin_bit_cast(unsigned int, f);
  unsigned int r = (u + 0x7fffu + ((u >> 16) & 1u)) >> 16;
  return (ushort_t)r;
}
__device__ __forceinline__ float bf2f(ushort_t h) {
  unsigned int u = ((unsigned int)h) << 16;
  return __builtin_bit_cast(float, u);
}

// ---------------- constant-matrix math (double precision) ----------------
__device__ double bmat_val(int w, int vv) {
  // column vv of (resize56->62 then rfft62, fwd ortho): vv<32 Re, else Im
  const int v = vv & 31;
  const bool isI = vv >= 32;
  double accR = 0.0, accI = 0.0;
  for (int wp = 0; wp < 62; ++wp) {
    const double src = (wp + 0.5) * (56.0 / 62.0) - 0.5;
    const int w0 = (int)floor(src);
    const double f = src - (double)w0;
    const double s0 = (w0 >= 0 && w0 <= 55) ? (1.0 - f) : 0.0;
    const double s1 = (w0 + 1 >= 0 && w0 + 1 <= 55) ? f : 0.0;
    const double ssum = s0 + s1;
    double wgt = 0.0;
    if (w == w0) wgt = s0 / ssum;
    else if (w == w0 + 1) wgt = s1 / ssum;
    if (wgt != 0.0) {
      const int p = (v * wp) % 62;
      const double ang = 6.283185307179586476925286766559 * (double)p / 62.0;
      accR += wgt * cos(ang);
      accI -= wgt * sin(ang);
    }
  }
  const double nrm = 1.0 / sqrt(3472.0);
  return (isI ? accI : accR) * nrm;
}

// DtStack component: v in [0,32), isI selects Im; wq = output column 0..55.
__device__ double dt_component(int v, bool isI, int wq) {
  const double ks = 62.0 / 56.0;
  const double src = (wq + 0.5) * ks - 0.5;
  double wsum = 0.0;
  for (int wp = 0; wp < 62; ++wp) {
    const double xx = fabs(src - (double)wp) / ks;
    if (xx < 1.0) wsum += 1.0 - xx;
  }
  const double cv = (v == 0 || v == 31) ? 1.0 : 2.0;
  double accR = 0.0, accI = 0.0;
  for (int wp = 0; wp < 62; ++wp) {
    const double xx = fabs(src - (double)wp) / ks;
    if (xx >= 1.0) continue;
    const double wgt = (1.0 - xx) / wsum;
    double cc, ss;
    if (v == 0)       { cc = 1.0; ss = 0.0; }
    else if (v == 31) { cc = (wp & 1) ? -1.0 : 1.0; ss = 0.0; }
    else {
      const int p = (v * wp) % 62;
      const double ang = 6.283185307179586476925286766559 * (double)p / 62.0;
      cc = cos(ang); ss = sin(ang);
    }
    accR += wgt * cv * cc;
    accI -= wgt * cv * ss;
  }
  const double nrm = 1.0 / sqrt(3472.0);
  return (isI ? accI : accR) * nrm;
}

__device__ __forceinline__ void emit_hilo(ushort_t* hp, ushort_t* lp, int off, double val) {
  const float fv = (float)val;
  const ushort_t h = f2bf(fv);
  const float hf = bf2f(h);
  const ushort_t l = f2bf((float)(val - (double)hf));
  hp[off] = h;
  lp[off] = l;
}

__global__ void k_const(const float* __restrict__ conv_w,
                        const float* __restrict__ basR, const float* __restrict__ basI,
                        ushort_t* BmT_h, ushort_t* BmT_l,
                        ushort_t* FARe_h, ushort_t* FARe_l,
                        ushort_t* FAIm_h, ushort_t* FAIm_l,
                        ushort_t* FDRe_h, ushort_t* FDRe_l,
                        ushort_t* FDIm_h, ushort_t* FDIm_l,
                        ushort_t* DtT_h, ushort_t* DtT_l,
                        ushort_t* W_h, ushort_t* W_l,
                        float* basRT, float* basIT) {
  const int idx = blockIdx.x * 256 + threadIdx.x;
  if (idx < 4096) {
    // BmT[vv][k=w], k>=56 zero
    const int vv = idx >> 6, k = idx & 63;
    const double v = (k < 56) ? bmat_val(k, vv) : 0.0;
    emit_hilo(BmT_h, BmT_l, idx, v);
  } else if (idx < 36864) {
    const int t = (idx - 4096) & 8191;
    const int which = (idx - 4096) >> 13;  // 0 FARe, 1 FAIm, 2 FDRe, 3 FDIm
    const int row = t >> 7, k = t & 127;
    double val = 0.0;
    if (row < 56 && k < 112) {
      const int h = (k < 56) ? k : k - 56;
      const double ang = 6.283185307179586476925286766559 *
                         (double)((row * h) % 56) / 56.0;
      const double c = cos(ang), s = sin(ang);
      const bool lowk = (k < 56);
      // fwd: e^{-i t} -> Re=[c|s], Im=[-s|c]; inv: e^{+i t} -> Re=[c|-s], Im=[s|c]
      if (which == 0)      val = lowk ? c : s;
      else if (which == 1) val = lowk ? -s : c;
      else if (which == 2) val = lowk ? c : -s;
      else                 val = lowk ? s : c;
    }
    ushort_t* hp = (which == 0) ? FARe_h : (which == 1) ? FAIm_h : (which == 2) ? FDRe_h : FDIm_h;
    ushort_t* lp = (which == 0) ? FARe_l : (which == 1) ? FAIm_l : (which == 2) ? FDRe_l : FDIm_l;
    emit_hilo(hp, lp, t, val);
  } else if (idx < 40960) {
    // DtT rows INTERLEAVED to match ta layout: kk = 2*v + isIm
    const int t = idx - 36864;
    const int w = t >> 6, kk = t & 63;
    const double val = (w < 56) ? dt_component(kk >> 1, (kk & 1) != 0, w) : 0.0;
    emit_hilo(DtT_h, DtT_l, t, val);
  } else if (idx < 106496) {
    const int t = idx - 40960;
    emit_hilo(W_h, W_l, t, (double)conv_w[t]);
  } else if (idx < 135168) {
    // transposed basis: basRT/basIT[q*8+k] = bas{R,I}[k*1792+q]
    const int t = idx - 106496;         // 0..28671
    const int tt = t - (t / 14336) * 14336;
    const int m2 = t / 14336;
    const int q = tt >> 3, k = tt & 7;
    if (m2 == 0) basRT[tt] = basR[k * 1792 + q];
    else         basIT[tt] = basI[k * 1792 + q];
  }
}

// ---------------- GAP ----------------
__global__ __launch_bounds__(256) void k_gap(const float* __restrict__ x,
                                             float* __restrict__ ctx) {
  const int img = blockIdx.x;
  const int tid = threadIdx.x;
  const float4* p4 = (const float4*)(x + (size_t)img * 3136);
  float s = 0.f;
  for (int i = tid; i < 784; i += 256) {
    const float4 v = p4[i];
    s += v.x + v.y + v.z + v.w;
  }
  for (int off = 32; off > 0; off >>= 1) s += __shfl_down(s, off, 64);
  __shared__ float ls[4];
  if ((tid & 63) == 0) ls[tid >> 6] = s;
  __syncthreads();
  if (tid == 0) ctx[img] = (ls[0] + ls[1] + ls[2] + ls[3]) * (1.0f / 3136.0f);
}

// ---------------- fc1 + LN + ReLU ----------------
__global__ void k_mlp(const float* __restrict__ ctx, const float* __restrict__ fc1_w,
                      const float* __restrict__ fc1_b, const float* __restrict__ ln_g,
                      const float* __restrict__ ln_b, float* __restrict__ hdn) {
  const int b = blockIdx.x;
  const int j = threadIdx.x;
  __shared__ float h[16];
  if (j < 16) {
    const float* cr = ctx + b * 256;
    const float* wr = fc1_w + j * 256;
    float acc = fc1_b[j];
    for (int c0 = 0; c0 < 256; ++c0) acc = fmaf(cr[c0], wr[c0], acc);
    h[j] = acc;
  }
  __syncthreads();
  if (j < 16) {
    float mu = 0.f, m2 = 0.f;
    for (int t = 0; t < 16; ++t) { mu += h[t]; m2 += h[t] * h[t]; }
    mu *= 0.0625f; m2 *= 0.0625f;
    const float var = m2 - mu * mu;
    const float val = (h[j] - mu) / sqrtf(var + 1e-5f) * ln_g[j] + ln_b[j];
    hdn[b * 16 + j] = fmaxf(val, 0.f);
  }
}

// ---------------- fourier head + softmax ----------------
__global__ __launch_bounds__(256) void k_coeffs(const float* __restrict__ hdn,
                                                const float* __restrict__ fh_w,
                                                const float* __restrict__ fh_b,
                                                float* __restrict__ coeffs) {
  const int gid = blockIdx.x * 256 + threadIdx.x;
  const int b = gid >> 12;
  const int cm = gid & 4095;
  float hv[16];
  const float* hp = hdn + b * 16;
#pragma unroll
  for (int j = 0; j < 16; ++j) hv[j] = hp[j];
  const int row0 = cm * 8;
  float a[8];
  float mx = -1e30f;
#pragma unroll
  for (int k = 0; k < 8; ++k) {
    const float* wr = fh_w + (size_t)(row0 + k) * 16;
    float acc = fh_b[row0 + k];
#pragma unroll
    for (int j = 0; j < 16; ++j) acc = fmaf(hv[j], wr[j], acc);
    a[k] = acc;
    mx = fmaxf(mx, acc);
  }
  float s = 0.f;
#pragma unroll
  for (int k = 0; k < 8; ++k) { a[k] = expf(a[k] - mx); s += a[k]; }
  const float inv = 1.f / s;
  float* outp = coeffs + (size_t)gid * 8;
#pragma unroll
  for (int k = 0; k < 8; ++k) outp[k] = a[k] * inv;
}

// ---------------- fused spectral branch: ONE WAVE per image, ONE LDS region ----
// 64-thread blocks, 9216 B LDS. The single region serves, in sequence:
//   x [64][72] -> x1T [32][136] -> x2T [32][136] -> ta [64][72]
// Each stage's output is held PACKED IN REGISTERS (~32 VGPRs, fully static
// indexing) until the input is dead, then written in place. x1T's zeroed K-pad
// (cols 112..127) persists under x2T (x2T writes only cols 0..111), so it is
// zeroed once.
// NOTE: plain __launch_bounds__(64) -- round-5's (64,4) capped VGPR at 128 and
// caused catastrophic scratch spilling (WRITE_SIZE 50MB->1.58GB). Let the
// allocator pick; <=128 VGPR gives 16 waves/CU, 129-256 gives 8 (= round-4).
__global__ __launch_bounds__(64) void k_fft(
    const float* __restrict__ x, const float* __restrict__ coeffs,
    const float* __restrict__ basRT, const float* __restrict__ basIT,
    const ushort_t* __restrict__ BmT_h, const ushort_t* __restrict__ BmT_l,
    const ushort_t* __restrict__ FARe_h, const ushort_t* __restrict__ FARe_l,
    const ushort_t* __restrict__ FAIm_h, const ushort_t* __restrict__ FAIm_l,
    const ushort_t* __restrict__ FDRe_h, const ushort_t* __restrict__ FDRe_l,
    const ushort_t* __restrict__ FDIm_h, const ushort_t* __restrict__ FDIm_l,
    const ushort_t* __restrict__ DtT_h, const ushort_t* __restrict__ DtT_l,
    ushort_t* __restrict__ ybf) {
  __shared__ __align__(16) ushort_t reg[4608];   // 9216 B
  const int img = blockIdx.x;
  const int lane = threadIdx.x;                  // 0..63
  const int col = lane & 15, quad = lane >> 4;
  const f32x4 zf = {0.f, 0.f, 0.f, 0.f};

  // ---- phase 1: zero x K-pads (rows<56, cols 56..63); load x -> reg ----
  {
#pragma unroll
    for (int i = 0; i < 4; ++i) {
      const int t = i * 64 + lane;
      if (t < 224) {
        const int h = t >> 2, c = t & 3;
        *(unsigned int*)&reg[h * 72 + 56 + c * 2] = 0u;
      }
    }
    const float4* xp = (const float4*)(x + (size_t)img * 3136);
    for (int f = lane; f < 784; f += 64) {
      const float4 v = xp[f];
      const int h = f / 14, w4 = (f % 14) * 4;
      s16x4 p;
      p[0] = (short)f2bf(v.x); p[1] = (short)f2bf(v.y);
      p[2] = (short)f2bf(v.z); p[3] = (short)f2bf(v.w);
      *(s16x4*)&reg[h * 72 + w4] = p;
    }
  }
  __syncthreads();

  // stage b: x1 = x @ Bmat; outputs held in hb, then reg overwritten as x1T
  {
    s16x4 hb[4][4];
#pragma unroll
    for (int mt = 0; mt < 4; ++mt) {
      const int arow = (mt * 16 + col) * 72;
      const s16x8 a0 = *(const s16x8*)&reg[arow + quad * 8];
      const s16x8 a1 = *(const s16x8*)&reg[arow + 32 + quad * 8];
#pragma unroll
      for (int nt = 0; nt < 4; ++nt) {
        const int nrow = nt * 16 + col;  // vv
        const s16x8 bh0 = *(const s16x8*)&BmT_h[nrow * 64 + quad * 8];
        const s16x8 bl0 = *(const s16x8*)&BmT_l[nrow * 64 + quad * 8];
        const s16x8 bh1 = *(const s16x8*)&BmT_h[nrow * 64 + 32 + quad * 8];
        const s16x8 bl1 = *(const s16x8*)&BmT_l[nrow * 64 + 32 + quad * 8];
        f32x4 acc = zf;
        acc = MFMA16(a0, bh0, acc);
        acc = MFMA16(a0, bl0, acc);
        acc = MFMA16(a1, bh1, acc);
        acc = MFMA16(a1, bl1, acc);
        s16x4 p;
        p[0] = (short)f2bf(acc[0]); p[1] = (short)f2bf(acc[1]);
        p[2] = (short)f2bf(acc[2]); p[3] = (short)f2bf(acc[3]);
        hb[mt][nt] = p;
      }
    }
    __syncthreads();   // all x reads done; reg may be overwritten
    // zero x1T K-pad: rows 0..31, cols 112..127 (persists under x2T too)
#pragma unroll
    for (int i = 0; i < 4; ++i) {
      const int t = i * 64 + lane;
      const int r = t >> 3, c = t & 7;
      *(unsigned int*)&reg[r * 136 + 112 + c * 2] = 0u;
    }
#pragma unroll
    for (int mt = 0; mt < 4; ++mt) {
      const int h0 = mt * 16 + quad * 4;
      if (h0 < 56) {
#pragma unroll
        for (int nt = 0; nt < 4; ++nt) {
          const int vr = (nt & 1) * 16 + col;
          const int kk = h0 + ((nt >= 2) ? 56 : 0);
          *(s16x4*)&reg[vr * 136 + kk] = hb[mt][nt];
        }
      }
    }
  }
  __syncthreads();

  // stage c: X2 = Fh_fwd @ x1, filter by inline-G; held in hcR/hcI -> reg as x2T
  {
    const float* co = coeffs + (size_t)img * 128;
    s16x4 hcR[4][2], hcI[4][2];
#pragma unroll
    for (int mt = 0; mt < 4; ++mt) {
      f32x4 accRe[2] = {zf, zf}, accIm[2] = {zf, zf};
#pragma unroll
      for (int ks = 0; ks < 4; ++ks) {
        const int aoff = (mt * 16 + col) * 128 + ks * 32 + quad * 8;
        const s16x8 aRh = *(const s16x8*)&FARe_h[aoff];
        const s16x8 aRl = *(const s16x8*)&FARe_l[aoff];
        const s16x8 aIh = *(const s16x8*)&FAIm_h[aoff];
        const s16x8 aIl = *(const s16x8*)&FAIm_l[aoff];
#pragma unroll
        for (int nt = 0; nt < 2; ++nt) {
          const s16x8 b = *(const s16x8*)&reg[(nt * 16 + col) * 136 + ks * 32 + quad * 8];
          accRe[nt] = MFMA16(aRh, b, accRe[nt]);
          accRe[nt] = MFMA16(aRl, b, accRe[nt]);
          accIm[nt] = MFMA16(aIh, b, accIm[nt]);
          accIm[nt] = MFMA16(aIl, b, accIm[nt]);
        }
      }
      const int u0 = mt * 16 + quad * 4;
#pragma unroll
      for (int nt = 0; nt < 2; ++nt) {
        const int v = nt * 16 + col;
        s16x4 pR, pI;
#pragma unroll
        for (int r = 0; r < 4; ++r) {
          const int u = u0 + r;
          const int q = u * 32 + v;
          const int m = (u / 14) * 4 + (v >> 3);
          const float4 c0 = *(const float4*)&co[m * 8];
          const float4 c1 = *(const float4*)&co[m * 8 + 4];
          const float4 br0 = *(const float4*)&basRT[q * 8];
          const float4 br1 = *(const float4*)&basRT[q * 8 + 4];
          const float4 bi0 = *(const float4*)&basIT[q * 8];
          const float4 bi1 = *(const float4*)&basIT[q * 8 + 4];
          float gr = 0.f, gi = 0.f;
          gr = fmaf(c0.x, br0.x, gr); gi = fmaf(c0.x, bi0.x, gi);
          gr = fmaf(c0.y, br0.y, gr); gi = fmaf(c0.y, bi0.y, gi);
          gr = fmaf(c0.z, br0.z, gr); gi = fmaf(c0.z, bi0.z, gi);
          gr = fmaf(c0.w, br0.w, gr); gi = fmaf(c0.w, bi0.w, gi);
          gr = fmaf(c1.x, br1.x, gr); gi = fmaf(c1.x, bi1.x, gi);
          gr = fmaf(c1.y, br1.y, gr); gi = fmaf(c1.y, bi1.y, gi);
          gr = fmaf(c1.z, br1.z, gr); gi = fmaf(c1.z, bi1.z, gi);
          gr = fmaf(c1.w, br1.w, gr); gi = fmaf(c1.w, bi1.w, gi);
          const float re = accRe[nt][r] * gr - accIm[nt][r] * gi;
          const float im = accRe[nt][r] * gi + accIm[nt][r] * gr;
          pR[r] = (short)f2bf(re);
          pI[r] = (short)f2bf(im);
        }
        hcR[mt][nt] = pR;
        hcI[mt][nt] = pI;
      }
    }
    __syncthreads();   // all x1T reads done
#pragma unroll
    for (int mt = 0; mt < 4; ++mt) {
      const int u0 = mt * 16 + quad * 4;
      if (u0 < 56) {
#pragma unroll
        for (int nt = 0; nt < 2; ++nt) {
          const int v = nt * 16 + col;
          *(s16x4*)&reg[v * 136 + u0] = hcR[mt][nt];
          *(s16x4*)&reg[v * 136 + 56 + u0] = hcI[mt][nt];
        }
      }
    }
  }
  __syncthreads();

  // stage d: T = Fh_inv @ X2f; held packed u32 -> reg as ta [h][2v Re,Im]
  {
    unsigned int hd[4][2][4];
#pragma unroll
    for (int mt = 0; mt < 4; ++mt) {
      f32x4 accRe[2] = {zf, zf}, accIm[2] = {zf, zf};
#pragma unroll
      for (int ks = 0; ks < 4; ++ks) {
        const int aoff = (mt * 16 + col) * 128 + ks * 32 + quad * 8;
        const s16x8 aRh = *(const s16x8*)&FDRe_h[aoff];
        const s16x8 aRl = *(const s16x8*)&FDRe_l[aoff];
        const s16x8 aIh = *(const s16x8*)&FDIm_h[aoff];
        const s16x8 aIl = *(const s16x8*)&FDIm_l[aoff];
#pragma unroll
        for (int nt = 0; nt < 2; ++nt) {
          const s16x8 b = *(const s16x8*)&reg[(nt * 16 + col) * 136 + ks * 32 + quad * 8];
          accRe[nt] = MFMA16(aRh, b, accRe[nt]);
          accRe[nt] = MFMA16(aRl, b, accRe[nt]);
          accIm[nt] = MFMA16(aIh, b, accIm[nt]);
          accIm[nt] = MFMA16(aIl, b, accIm[nt]);
        }
      }
#pragma unroll
      for (int nt = 0; nt < 2; ++nt) {
#pragma unroll
        for (int r = 0; r < 4; ++r) {
          hd[mt][nt][r] = (unsigned int)f2bf(accRe[nt][r]) |
                          ((unsigned int)f2bf(accIm[nt][r]) << 16);
        }
      }
    }
    __syncthreads();   // all x2T reads done
#pragma unroll
    for (int mt = 0; mt < 4; ++mt) {
      const int h0 = mt * 16 + quad * 4;
#pragma unroll
      for (int nt = 0; nt < 2; ++nt) {
        const int v = nt * 16 + col;
#pragma unroll
        for (int r = 0; r < 4; ++r) {
          *(unsigned int*)&reg[(h0 + r) * 72 + 2 * v] = hd[mt][nt][r];
        }
      }
    }
  }
  __syncthreads();

  // stage e: y = T @ DtStack (K=64, rows interleaved to match ta), store bf16
  {
    ushort_t* yo = ybf + (size_t)img * 3136;
#pragma unroll
    for (int mt = 0; mt < 4; ++mt) {
      const int arow = (mt * 16 + col) * 72;
      const s16x8 a0 = *(const s16x8*)&reg[arow + quad * 8];
      const s16x8 a1 = *(const s16x8*)&reg[arow + 32 + quad * 8];
      const int h0 = mt * 16 + quad * 4;
#pragma unroll
      for (int nt = 0; nt < 4; ++nt) {
        const int w = nt * 16 + col;
        const s16x8 bh0 = *(const s16x8*)&DtT_h[w * 64 + quad * 8];
        const s16x8 bl0 = *(const s16x8*)&DtT_l[w * 64 + quad * 8];
        const s16x8 bh1 = *(const s16x8*)&DtT_h[w * 64 + 32 + quad * 8];
        const s16x8 bl1 = *(const s16x8*)&DtT_l[w * 64 + 32 + quad * 8];
        f32x4 acc = zf;
        acc = MFMA16(a0, bh0, acc);
        acc = MFMA16(a0, bl0, acc);
        acc = MFMA16(a1, bh1, acc);
        acc = MFMA16(a1, bl1, acc);
        if (h0 < 56 && w < 56) {
#pragma unroll
          for (int r = 0; r < 4; ++r) yo[(h0 + r) * 56 + w] = f2bf(acc[r]);
        }
      }
    }
  }
}

// ---------------- 1x1 conv via MFMA: A=W(hi/lo), B=y bf16 direct from global ----------------
__global__ __launch_bounds__(256) void k_conv(const ushort_t* __restrict__ ybf,
                                              const ushort_t* __restrict__ W_h,
                                              const ushort_t* __restrict__ W_l,
                                              float* __restrict__ z) {
  const int pb = blockIdx.x;   // 0..12, 256 pixels each (last ragged)
  const int oh = blockIdx.y;   // 0..1, 128 out-channels each
  const int b = blockIdx.z;
  const int tid = threadIdx.x;
  const int wave = tid >> 6, lane = tid & 63, col = lane & 15, quad = lane >> 4;
  const f32x4 zf = {0.f, 0.f, 0.f, 0.f};
  f32x4 acc[8][4];
#pragma unroll
  for (int mt = 0; mt < 8; ++mt)
#pragma unroll
    for (int i = 0; i < 4; ++i) acc[mt][i] = zf;

  const size_t ybase = (size_t)b * 256 * 3136;
  int p0i[4];
  bool act[4];
#pragma unroll
  for (int i = 0; i < 4; ++i) {
    p0i[i] = pb * 256 + (wave * 4 + i) * 16;
    act[i] = p0i[i] < 3136;
  }

  for (int ks = 0; ks < 8; ++ks) {
    const int c0 = ks * 32 + quad * 8;
    s16x8 bfr[4];
#pragma unroll
    for (int i = 0; i < 4; ++i) {
      if (act[i]) {
        s16x8 t;
#pragma unroll
        for (int j = 0; j < 8; ++j)
          t[j] = (short)ybf[ybase + (size_t)(c0 + j) * 3136 + p0i[i] + col];
        bfr[i] = t;
      }
    }
#pragma unroll
    for (int mt = 0; mt < 8; ++mt) {
      const int orow = oh * 128 + mt * 16 + col;
      const s16x8 ah = *(const s16x8*)&W_h[orow * 256 + ks * 32 + quad * 8];
      const s16x8 al = *(const s16x8*)&W_l[orow * 256 + ks * 32 + quad * 8];
#pragma unroll
      for (int i = 0; i < 4; ++i) {
        if (act[i]) {
          acc[mt][i] = MFMA16(ah, bfr[i], acc[mt][i]);
          acc[mt][i] = MFMA16(al, bfr[i], acc[mt][i]);
        }
      }
    }
  }

#pragma unroll
  for (int mt = 0; mt < 8; ++mt) {
#pragma unroll
    for (int i = 0; i < 4; ++i) {
      if (!act[i]) continue;
#pragma unroll
      for (int r = 0; r < 4; ++r) {
        const int o = oh * 128 + mt * 16 + quad * 4 + r;
        z[((size_t)b * 256 + o) * 3136 + p0i[i] + col] = acc[mt][i][r];
      }
    }
  }
}

// ---------------- BN sums over z ----------------
__global__ __launch_bounds__(256) void k_bnsum(const float* __restrict__ z,
                                               float* __restrict__ bnsum,
                                               float* __restrict__ bnsq) {
  const int bo = blockIdx.x;  // b*256+o
  const int tid = threadIdx.x;
  const float4* p4 = (const float4*)(z + (size_t)bo * 3136);
  float s = 0.f, s2 = 0.f;
  for (int i = tid; i < 784; i += 256) {
    const float4 v = p4[i];
    s += v.x + v.y + v.z + v.w;
    s2 += v.x * v.x + v.y * v.y + v.z * v.z + v.w * v.w;
  }
  for (int off = 32; off > 0; off >>= 1) {
    s += __shfl_down(s, off, 64);
    s2 += __shfl_down(s2, off, 64);
  }
  __shared__ float ls[8];
  if ((tid & 63) == 0) { ls[tid >> 6] = s; ls[4 + (tid >> 6)] = s2; }
  __syncthreads();
  if (tid == 0) {
    atomicAdd(bnsum + (bo & 255), ls[0] + ls[1] + ls[2] + ls[3]);
    atomicAdd(bnsq + (bo & 255), ls[4] + ls[5] + ls[6] + ls[7]);
  }
}

__global__ void k_bnstats(const float* __restrict__ bnsum, const float* __restrict__ bnsq,
                          const float* __restrict__ bn_g, const float* __restrict__ bn_b,
                          float* __restrict__ scale, float* __restrict__ shift) {
  const int o = threadIdx.x;
  if (o < 256) {
    const float N = 32.f * 3136.f;
    const float m = bnsum[o] / N;
    const float v = bnsq[o] / N - m * m;
    const float sc = bn_g[o] / sqrtf(v + 1e-5f);
    scale[o] = sc;
    shift[o] = bn_b[o] - m * sc;
  }
}

__global__ __launch_bounds__(256) void k_bnapply(float* __restrict__ z,
                                                 const float* __restrict__ scale,
                                                 const float* __restrict__ shift) {
  const size_t i = ((size_t)blockIdx.x * 256 + threadIdx.x) * 4;
  const int ch = (int)((i / 3136) & 255);
  const float sc = scale[ch], sh = shift[ch];
  float4 v = *(float4*)(z + i);
  v.x = fmaf(v.x, sc, sh);
  v.y = fmaf(v.y, sc, sh);
  v.z = fmaf(v.z, sc, sh);
  v.w = fmaf(v.w, sc, sh);
  *(float4*)(z + i) = v;
}

extern "C" void kernel_launch(void* const* d_in, const int* in_sizes, int n_in,
                              void* d_out, int out_size, void* d_ws, size_t ws_size,
                              hipStream_t stream) {
  const float* x          = (const float*)d_in[0];
  const float* fc1_w      = (const float*)d_in[1];
  const float* fc1_b      = (const float*)d_in[2];
  const float* ln_g       = (const float*)d_in[3];
  const float* ln_b       = (const float*)d_in[4];
  const float* fh_w       = (const float*)d_in[5];
  const float* fh_b       = (const float*)d_in[6];
  const float* basis_real = (const float*)d_in[7];
  const float* basis_imag = (const float*)d_in[8];
  const float* conv_w     = (const float*)d_in[9];
  const float* bn_g       = (const float*)d_in[10];
  const float* bn_b       = (const float*)d_in[11];
  float* out = (float*)d_out;
  char* ws = (char*)d_ws;
  (void)in_sizes; (void)n_in; (void)out_size; (void)ws_size;

  float* ctx   = (float*)(ws + WO_CTX);
  float* hdn   = (float*)(ws + WO_HDN);
  float* bnsum = (float*)(ws + WO_BNSUM);
  float* bnsq  = (float*)(ws + WO_BNSQ);
  float* scale = (float*)(ws + WO_SCALE);
  float* shift = (float*)(ws + WO_SHIFT);
  float* coef  = (float*)(ws + WO_COEF);
  ushort_t* BmT_h  = (ushort_t*)(ws + WO_BMT_H);
  ushort_t* BmT_l  = (ushort_t*)(ws + WO_BMT_L);
  ushort_t* FARe_h = (ushort_t*)(ws + WO_FARE_H);
  ushort_t* FARe_l = (ushort_t*)(ws + WO_FARE_L);
  ushort_t* FAIm_h = (ushort_t*)(ws + WO_FAIM_H);
  ushort_t* FAIm_l = (ushort_t*)(ws + WO_FAIM_L);
  ushort_t* FDRe_h = (ushort_t*)(ws + WO_FDRE_H);
  ushort_t* FDRe_l = (ushort_t*)(ws + WO_FDRE_L);
  ushort_t* FDIm_h = (ushort_t*)(ws + WO_FDIM_H);
  ushort_t* FDIm_l = (ushort_t*)(ws + WO_FDIM_L);
  ushort_t* DtT_h  = (ushort_t*)(ws + WO_DTT_H);
  ushort_t* DtT_l  = (ushort_t*)(ws + WO_DTT_L);
  ushort_t* W_h    = (ushort_t*)(ws + WO_CW_H);
  ushort_t* W_l    = (ushort_t*)(ws + WO_CW_L);
  ushort_t* ybf    = (ushort_t*)(ws + WO_YBF);
  float* basRT = (float*)(ws + WO_BASRT);
  float* basIT = (float*)(ws + WO_BASIT);

  hipMemsetAsync(bnsum, 0, 2048, stream);  // bnsum+bnsq contiguous

  hipLaunchKernelGGL(k_const, dim3(528), dim3(256), 0, stream,
                     conv_w, basis_real, basis_imag,
                     BmT_h, BmT_l, FARe_h, FARe_l, FAIm_h, FAIm_l,
                     FDRe_h, FDRe_l, FDIm_h, FDIm_l, DtT_h, DtT_l, W_h, W_l,
                     basRT, basIT);
  hipLaunchKernelGGL(k_gap, dim3(8192), dim3(256), 0, stream, x, ctx);
  hipLaunchKernelGGL(k_mlp, dim3(32), dim3(64), 0, stream,
                     ctx, fc1_w, fc1_b, ln_g, ln_b, hdn);
  hipLaunchKernelGGL(k_coeffs, dim3(512), dim3(256), 0, stream, hdn, fh_w, fh_b, coef);
  hipLaunchKernelGGL(k_fft, dim3(8192), dim3(64), 0, stream,
                     x, coef, basRT, basIT,
                     BmT_h, BmT_l, FARe_h, FARe_l, FAIm_h, FAIm_l,
                     FDRe_h, FDRe_l, FDIm_h, FDIm_l, DtT_h, DtT_l, ybf);
  hipLaunchKernelGGL(k_conv, dim3(13, 2, 32), dim3(256), 0, stream, ybf, W_h, W_l, out);
  hipLaunchKernelGGL(k_bnsum, dim3(8192), dim3(256), 0, stream, out, bnsum, bnsq);
  hipLaunchKernelGGL(k_bnstats, dim3(1), dim3(256), 0, stream,
                     bnsum, bnsq, bn_g, bn_b, scale, shift);
  hipLaunchKernelGGL(k_bnapply, dim3(25088), dim3(256), 0, stream, out, scale, shift);
}

// Round 7
// 629.594 us; speedup vs baseline: 1.9957x; 1.3996x over previous
//
#include <hip/hip_runtime.h>
#include <math.h>

typedef __attribute__((ext_vector_type(4))) float f32x4;
typedef __attribute__((ext_vector_type(8))) short s16x8;
typedef __attribute__((ext_vector_type(4))) short s16x4;
typedef unsigned short ushort_t;

#define MFMA16(a, b, c) __builtin_amdgcn_mfma_f32_16x16x32_bf16((a), (b), (c), 0, 0, 0)

// ---------------- workspace byte offsets ----------------
#define WO_CTX    0u          // 32768
#define WO_HDN    32768u      // 2048
#define WO_BNSUM  34816u      // 1024
#define WO_BNSQ   35840u      // 1024
#define WO_SCALE  36864u      // 1024
#define WO_SHIFT  37888u      // 1024
#define WO_COEF   40960u      // 4194304
#define WO_BMT_H  4235264u    // 8192  (64x64 bf16)
#define WO_BMT_L  4243456u
#define WO_FARE_H 4251648u    // 16384 (64x128)
#define WO_FARE_L 4268032u
#define WO_FAIM_H 4284416u
#define WO_FAIM_L 4300800u
#define WO_FDRE_H 4317184u
#define WO_FDRE_L 4333568u
#define WO_FDIM_H 4349952u
#define WO_FDIM_L 4366336u
#define WO_DTT_H  4382720u    // 8192 (64x64)
#define WO_DTT_L  4390912u
#define WO_CW_H   4399104u    // 131072 (256x256)
#define WO_CW_L   4530176u
#define WO_YBF    4661248u    // 51380224 (8192*3136 bf16)
#define WO_BASRT  56041472u   // 57344 (1792x8 fp32, [q][k])
#define WO_BASIT  56098816u   // 57344

__device__ __forceinline__ ushort_t f2bf(float f) {
  unsigned int u = __builtin_bit_cast(unsigned int, f);
  unsigned int r = (u + 0x7fffu + ((u >> 16) & 1u)) >> 16;
  return (ushort_t)r;
}
__device__ __forceinline__ float bf2f(ushort_t h) {
  unsigned int u = ((unsigned int)h) << 16;
  return __builtin_bit_cast(float, u);
}

// ---------------- constant-matrix math (double precision) ----------------
__device__ double bmat_val(int w, int vv) {
  // column vv of (resize56->62 then rfft62, fwd ortho): vv<32 Re, else Im
  const int v = vv & 31;
  const bool isI = vv >= 32;
  double accR = 0.0, accI = 0.0;
  for (int wp = 0; wp < 62; ++wp) {
    const double src = (wp + 0.5) * (56.0 / 62.0) - 0.5;
    const int w0 = (int)floor(src);
    const double f = src - (double)w0;
    const double s0 = (w0 >= 0 && w0 <= 55) ? (1.0 - f) : 0.0;
    const double s1 = (w0 + 1 >= 0 && w0 + 1 <= 55) ? f : 0.0;
    const double ssum = s0 + s1;
    double wgt = 0.0;
    if (w == w0) wgt = s0 / ssum;
    else if (w == w0 + 1) wgt = s1 / ssum;
    if (wgt != 0.0) {
      const int p = (v * wp) % 62;
      const double ang = 6.283185307179586476925286766559 * (double)p / 62.0;
      accR += wgt * cos(ang);
      accI -= wgt * sin(ang);
    }
  }
  const double nrm = 1.0 / sqrt(3472.0);
  return (isI ? accI : accR) * nrm;
}

// DtStack component: v in [0,32), isI selects Im; wq = output column 0..55.
__device__ double dt_component(int v, bool isI, int wq) {
  const double ks = 62.0 / 56.0;
  const double src = (wq + 0.5) * ks - 0.5;
  double wsum = 0.0;
  for (int wp = 0; wp < 62; ++wp) {
    const double xx = fabs(src - (double)wp) / ks;
    if (xx < 1.0) wsum += 1.0 - xx;
  }
  const double cv = (v == 0 || v == 31) ? 1.0 : 2.0;
  double accR = 0.0, accI = 0.0;
  for (int wp = 0; wp < 62; ++wp) {
    const double xx = fabs(src - (double)wp) / ks;
    if (xx >= 1.0) continue;
    const double wgt = (1.0 - xx) / wsum;
    double cc, ss;
    if (v == 0)       { cc = 1.0; ss = 0.0; }
    else if (v == 31) { cc = (wp & 1) ? -1.0 : 1.0; ss = 0.0; }
    else {
      const int p = (v * wp) % 62;
      const double ang = 6.283185307179586476925286766559 * (double)p / 62.0;
      cc = cos(ang); ss = sin(ang);
    }
    accR += wgt * cv * cc;
    accI -= wgt * cv * ss;
  }
  const double nrm = 1.0 / sqrt(3472.0);
  return (isI ? accI : accR) * nrm;
}

__device__ __forceinline__ void emit_hilo(ushort_t* hp, ushort_t* lp, int off, double val) {
  const float fv = (float)val;
  const ushort_t h = f2bf(fv);
  const float hf = bf2f(h);
  const ushort_t l = f2bf((float)(val - (double)hf));
  hp[off] = h;
  lp[off] = l;
}

__global__ void k_const(const float* __restrict__ conv_w,
                        const float* __restrict__ basR, const float* __restrict__ basI,
                        ushort_t* BmT_h, ushort_t* BmT_l,
                        ushort_t* FARe_h, ushort_t* FARe_l,
                        ushort_t* FAIm_h, ushort_t* FAIm_l,
                        ushort_t* FDRe_h, ushort_t* FDRe_l,
                        ushort_t* FDIm_h, ushort_t* FDIm_l,
                        ushort_t* DtT_h, ushort_t* DtT_l,
                        ushort_t* W_h, ushort_t* W_l,
                        float* basRT, float* basIT) {
  const int idx = blockIdx.x * 256 + threadIdx.x;
  if (idx < 4096) {
    // BmT[vv][k=w], k>=56 zero
    const int vv = idx >> 6, k = idx & 63;
    const double v = (k < 56) ? bmat_val(k, vv) : 0.0;
    emit_hilo(BmT_h, BmT_l, idx, v);
  } else if (idx < 36864) {
    const int t = (idx - 4096) & 8191;
    const int which = (idx - 4096) >> 13;  // 0 FARe, 1 FAIm, 2 FDRe, 3 FDIm
    const int row = t >> 7, k = t & 127;
    double val = 0.0;
    if (row < 56 && k < 112) {
      const int h = (k < 56) ? k : k - 56;
      const double ang = 6.283185307179586476925286766559 *
                         (double)((row * h) % 56) / 56.0;
      const double c = cos(ang), s = sin(ang);
      const bool lowk = (k < 56);
      // fwd: e^{-i t} -> Re=[c|s], Im=[-s|c]; inv: e^{+i t} -> Re=[c|-s], Im=[s|c]
      if (which == 0)      val = lowk ? c : s;
      else if (which == 1) val = lowk ? -s : c;
      else if (which == 2) val = lowk ? c : -s;
      else                 val = lowk ? s : c;
    }
    ushort_t* hp = (which == 0) ? FARe_h : (which == 1) ? FAIm_h : (which == 2) ? FDRe_h : FDIm_h;
    ushort_t* lp = (which == 0) ? FARe_l : (which == 1) ? FAIm_l : (which == 2) ? FDRe_l : FDIm_l;
    emit_hilo(hp, lp, t, val);
  } else if (idx < 40960) {
    // DtT rows INTERLEAVED to match ta layout: kk = 2*v + isIm
    const int t = idx - 36864;
    const int w = t >> 6, kk = t & 63;
    const double val = (w < 56) ? dt_component(kk >> 1, (kk & 1) != 0, w) : 0.0;
    emit_hilo(DtT_h, DtT_l, t, val);
  } else if (idx < 106496) {
    const int t = idx - 40960;
    emit_hilo(W_h, W_l, t, (double)conv_w[t]);
  } else if (idx < 135168) {
    // transposed basis: basRT/basIT[q*8+k] = bas{R,I}[k*1792+q]
    const int t = idx - 106496;         // 0..28671
    const int tt = t - (t / 14336) * 14336;
    const int m2 = t / 14336;
    const int q = tt >> 3, k = tt & 7;
    if (m2 == 0) basRT[tt] = basR[k * 1792 + q];
    else         basIT[tt] = basI[k * 1792 + q];
  }
}

// ---------------- GAP ----------------
__global__ __launch_bounds__(256) void k_gap(const float* __restrict__ x,
                                             float* __restrict__ ctx) {
  const int img = blockIdx.x;
  const int tid = threadIdx.x;
  const float4* p4 = (const float4*)(x + (size_t)img * 3136);
  float s = 0.f;
  for (int i = tid; i < 784; i += 256) {
    const float4 v = p4[i];
    s += v.x + v.y + v.z + v.w;
  }
  for (int off = 32; off > 0; off >>= 1) s += __shfl_down(s, off, 64);
  __shared__ float ls[4];
  if ((tid & 63) == 0) ls[tid >> 6] = s;
  __syncthreads();
  if (tid == 0) ctx[img] = (ls[0] + ls[1] + ls[2] + ls[3]) * (1.0f / 3136.0f);
}

// ---------------- fc1 + LN + ReLU ----------------
__global__ void k_mlp(const float* __restrict__ ctx, const float* __restrict__ fc1_w,
                      const float* __restrict__ fc1_b, const float* __restrict__ ln_g,
                      const float* __restrict__ ln_b, float* __restrict__ hdn) {
  const int b = blockIdx.x;
  const int j = threadIdx.x;
  __shared__ float h[16];
  if (j < 16) {
    const float* cr = ctx + b * 256;
    const float* wr = fc1_w + j * 256;
    float acc = fc1_b[j];
    for (int c0 = 0; c0 < 256; ++c0) acc = fmaf(cr[c0], wr[c0], acc);
    h[j] = acc;
  }
  __syncthreads();
  if (j < 16) {
    float mu = 0.f, m2 = 0.f;
    for (int t = 0; t < 16; ++t) { mu += h[t]; m2 += h[t] * h[t]; }
    mu *= 0.0625f; m2 *= 0.0625f;
    const float var = m2 - mu * mu;
    const float val = (h[j] - mu) / sqrtf(var + 1e-5f) * ln_g[j] + ln_b[j];
    hdn[b * 16 + j] = fmaxf(val, 0.f);
  }
}

// ---------------- fourier head + softmax ----------------
__global__ __launch_bounds__(256) void k_coeffs(const float* __restrict__ hdn,
                                                const float* __restrict__ fh_w,
                                                const float* __restrict__ fh_b,
                                                float* __restrict__ coeffs) {
  const int gid = blockIdx.x * 256 + threadIdx.x;
  const int b = gid >> 12;
  const int cm = gid & 4095;
  float hv[16];
  const float* hp = hdn + b * 16;
#pragma unroll
  for (int j = 0; j < 16; ++j) hv[j] = hp[j];
  const int row0 = cm * 8;
  float a[8];
  float mx = -1e30f;
#pragma unroll
  for (int k = 0; k < 8; ++k) {
    const float* wr = fh_w + (size_t)(row0 + k) * 16;
    float acc = fh_b[row0 + k];
#pragma unroll
    for (int j = 0; j < 16; ++j) acc = fmaf(hv[j], wr[j], acc);
    a[k] = acc;
    mx = fmaxf(mx, acc);
  }
  float s = 0.f;
#pragma unroll
  for (int k = 0; k < 8; ++k) { a[k] = expf(a[k] - mx); s += a[k]; }
  const float inv = 1.f / s;
  float* outp = coeffs + (size_t)gid * 8;
#pragma unroll
  for (int k = 0; k < 8; ++k) outp[k] = a[k] * inv;
}

// ---------------- fused spectral branch: ONE WAVE per image (round-4 proven) ----
// 64-thread blocks; whole b->c->d->e chain in a single wave; __syncthreads()
// degenerates to waitcnt + immediately-retiring s_barrier. Two 9216 B LDS
// regions with lifetime overlays (regA: x -> x2T; regB: x1T -> ta).
// 18432 B/block -> 8 blocks/CU at VGPR=96. Measured 219 us (round 4).
// Single-region + reg-held variants spill structurally (rounds 5/6) - do not retry.
__global__ __launch_bounds__(64) void k_fft(
    const float* __restrict__ x, const float* __restrict__ coeffs,
    const float* __restrict__ basRT, const float* __restrict__ basIT,
    const ushort_t* __restrict__ BmT_h, const ushort_t* __restrict__ BmT_l,
    const ushort_t* __restrict__ FARe_h, const ushort_t* __restrict__ FARe_l,
    const ushort_t* __restrict__ FAIm_h, const ushort_t* __restrict__ FAIm_l,
    const ushort_t* __restrict__ FDRe_h, const ushort_t* __restrict__ FDRe_l,
    const ushort_t* __restrict__ FDIm_h, const ushort_t* __restrict__ FDIm_l,
    const ushort_t* __restrict__ DtT_h, const ushort_t* __restrict__ DtT_l,
    ushort_t* __restrict__ ybf) {
  __shared__ __align__(16) ushort_t regA[4608];  // 9216 B: x [64][72] -> x2T [32][136]
  __shared__ __align__(16) ushort_t regB[4608];  // 9216 B: x1T [32][136] -> ta [64][72]
  const int img = blockIdx.x;
  const int lane = threadIdx.x;                  // 0..63
  const int col = lane & 15, quad = lane >> 4;
  const f32x4 zf = {0.f, 0.f, 0.f, 0.f};

  // ---- phase 1: zero K-pads; load x -> regA ----
  {
#pragma unroll
    for (int i = 0; i < 4; ++i) {                // xa rows 0..55, cols 56..63
      const int t = i * 64 + lane;
      if (t < 224) {
        const int h = t >> 2, c = t & 3;
        *(unsigned int*)&regA[h * 72 + 56 + c * 2] = 0u;
      }
    }
#pragma unroll
    for (int i = 0; i < 4; ++i) {                // x1T rows 0..31, cols 112..127
      const int t = i * 64 + lane;
      const int r = t >> 3, c = t & 7;
      *(unsigned int*)&regB[r * 136 + 112 + c * 2] = 0u;
    }
    const float4* xp = (const float4*)(x + (size_t)img * 3136);
    for (int f = lane; f < 784; f += 64) {
      const float4 v = xp[f];
      const int h = f / 14, w4 = (f % 14) * 4;
      s16x4 p;
      p[0] = (short)f2bf(v.x); p[1] = (short)f2bf(v.y);
      p[2] = (short)f2bf(v.z); p[3] = (short)f2bf(v.w);
      *(s16x4*)&regA[h * 72 + w4] = p;
    }
  }
  __syncthreads();

  // stage b: x1 = x @ Bmat  (M=56 pad 64, N=64, K=56 pad 64) -> regB
#pragma unroll
  for (int mt = 0; mt < 4; ++mt) {
    const int arow = (mt * 16 + col) * 72;
    const s16x8 a0 = *(const s16x8*)&regA[arow + quad * 8];
    const s16x8 a1 = *(const s16x8*)&regA[arow + 32 + quad * 8];
    const int h0 = mt * 16 + quad * 4;
#pragma unroll
    for (int nt = 0; nt < 4; ++nt) {
      const int nrow = nt * 16 + col;  // vv
      const s16x8 bh0 = *(const s16x8*)&BmT_h[nrow * 64 + quad * 8];
      const s16x8 bl0 = *(const s16x8*)&BmT_l[nrow * 64 + quad * 8];
      const s16x8 bh1 = *(const s16x8*)&BmT_h[nrow * 64 + 32 + quad * 8];
      const s16x8 bl1 = *(const s16x8*)&BmT_l[nrow * 64 + 32 + quad * 8];
      f32x4 acc = zf;
      acc = MFMA16(a0, bh0, acc);
      acc = MFMA16(a0, bl0, acc);
      acc = MFMA16(a1, bh1, acc);
      acc = MFMA16(a1, bl1, acc);
      if (h0 < 56) {
        s16x4 p;
        p[0] = (short)f2bf(acc[0]); p[1] = (short)f2bf(acc[1]);
        p[2] = (short)f2bf(acc[2]); p[3] = (short)f2bf(acc[3]);
        const int vr = nrow & 31;
        const int kk = (nrow < 32) ? h0 : 56 + h0;
        *(s16x4*)&regB[vr * 136 + kk] = p;
      }
    }
  }
  __syncthreads();

  // stage c: X2 = Fh_fwd @ x1, filter by inline-G -> regA (x dead, reused as x2T)
  {
    // zero x2T K-pad cols 112..127 (regA holds stale x bits there)
#pragma unroll
    for (int i = 0; i < 4; ++i) {
      const int t = i * 64 + lane;
      const int r = t >> 3, c = t & 7;
      *(unsigned int*)&regA[r * 136 + 112 + c * 2] = 0u;
    }
    const float* co = coeffs + (size_t)img * 128;
#pragma unroll
    for (int mt = 0; mt < 4; ++mt) {
      f32x4 accRe[2] = {zf, zf}, accIm[2] = {zf, zf};
#pragma unroll
      for (int ks = 0; ks < 4; ++ks) {
        const int aoff = (mt * 16 + col) * 128 + ks * 32 + quad * 8;
        const s16x8 aRh = *(const s16x8*)&FARe_h[aoff];
        const s16x8 aRl = *(const s16x8*)&FARe_l[aoff];
        const s16x8 aIh = *(const s16x8*)&FAIm_h[aoff];
        const s16x8 aIl = *(const s16x8*)&FAIm_l[aoff];
#pragma unroll
        for (int nt = 0; nt < 2; ++nt) {
          const s16x8 b = *(const s16x8*)&regB[(nt * 16 + col) * 136 + ks * 32 + quad * 8];
          accRe[nt] = MFMA16(aRh, b, accRe[nt]);
          accRe[nt] = MFMA16(aRl, b, accRe[nt]);
          accIm[nt] = MFMA16(aIh, b, accIm[nt]);
          accIm[nt] = MFMA16(aIl, b, accIm[nt]);
        }
      }
      const int u0 = mt * 16 + quad * 4;
      if (u0 < 56) {
#pragma unroll
        for (int nt = 0; nt < 2; ++nt) {
          const int v = nt * 16 + col;
          s16x4 pR, pI;
#pragma unroll
          for (int r = 0; r < 4; ++r) {
            const int u = u0 + r;
            const int q = u * 32 + v;
            const int m = (u / 14) * 4 + (v >> 3);
            const float4 c0 = *(const float4*)&co[m * 8];
            const float4 c1 = *(const float4*)&co[m * 8 + 4];
            const float4 br0 = *(const float4*)&basRT[q * 8];
            const float4 br1 = *(const float4*)&basRT[q * 8 + 4];
            const float4 bi0 = *(const float4*)&basIT[q * 8];
            const float4 bi1 = *(const float4*)&basIT[q * 8 + 4];
            float gr = 0.f, gi = 0.f;
            gr = fmaf(c0.x, br0.x, gr); gi = fmaf(c0.x, bi0.x, gi);
            gr = fmaf(c0.y, br0.y, gr); gi = fmaf(c0.y, bi0.y, gi);
            gr = fmaf(c0.z, br0.z, gr); gi = fmaf(c0.z, bi0.z, gi);
            gr = fmaf(c0.w, br0.w, gr); gi = fmaf(c0.w, bi0.w, gi);
            gr = fmaf(c1.x, br1.x, gr); gi = fmaf(c1.x, bi1.x, gi);
            gr = fmaf(c1.y, br1.y, gr); gi = fmaf(c1.y, bi1.y, gi);
            gr = fmaf(c1.z, br1.z, gr); gi = fmaf(c1.z, bi1.z, gi);
            gr = fmaf(c1.w, br1.w, gr); gi = fmaf(c1.w, bi1.w, gi);
            const float re = accRe[nt][r] * gr - accIm[nt][r] * gi;
            const float im = accRe[nt][r] * gi + accIm[nt][r] * gr;
            pR[r] = (short)f2bf(re);
            pI[r] = (short)f2bf(im);
          }
          *(s16x4*)&regA[v * 136 + u0] = pR;
          *(s16x4*)&regA[v * 136 + 56 + u0] = pI;
        }
      }
    }
  }
  __syncthreads();

  // stage d: T = Fh_inv @ X2f -> regB (x1T dead, reused as ta [h][2v])
#pragma unroll
  for (int mt = 0; mt < 4; ++mt) {
    f32x4 accRe[2] = {zf, zf}, accIm[2] = {zf, zf};
#pragma unroll
    for (int ks = 0; ks < 4; ++ks) {
      const int aoff = (mt * 16 + col) * 128 + ks * 32 + quad * 8;
      const s16x8 aRh = *(const s16x8*)&FDRe_h[aoff];
      const s16x8 aRl = *(const s16x8*)&FDRe_l[aoff];
      const s16x8 aIh = *(const s16x8*)&FDIm_h[aoff];
      const s16x8 aIl = *(const s16x8*)&FDIm_l[aoff];
#pragma unroll
      for (int nt = 0; nt < 2; ++nt) {
        const s16x8 b = *(const s16x8*)&regA[(nt * 16 + col) * 136 + ks * 32 + quad * 8];
        accRe[nt] = MFMA16(aRh, b, accRe[nt]);
        accRe[nt] = MFMA16(aRl, b, accRe[nt]);
        accIm[nt] = MFMA16(aIh, b, accIm[nt]);
        accIm[nt] = MFMA16(aIl, b, accIm[nt]);
      }
    }
    const int h0 = mt * 16 + quad * 4;  // rows >=56 write zeros (FhD rows zeroed)
#pragma unroll
    for (int nt = 0; nt < 2; ++nt) {
      const int v = nt * 16 + col;
#pragma unroll
      for (int r = 0; r < 4; ++r) {
        const unsigned int pk = (unsigned int)f2bf(accRe[nt][r]) |
                                ((unsigned int)f2bf(accIm[nt][r]) << 16);
        *(unsigned int*)&regB[(h0 + r) * 72 + 2 * v] = pk;
      }
    }
  }
  __syncthreads();

  // stage e: y = T @ DtStack (K=64, rows interleaved to match ta), store bf16
  {
    ushort_t* yo = ybf + (size_t)img * 3136;
#pragma unroll
    for (int mt = 0; mt < 4; ++mt) {
      const int arow = (mt * 16 + col) * 72;
      const s16x8 a0 = *(const s16x8*)&regB[arow + quad * 8];
      const s16x8 a1 = *(const s16x8*)&regB[arow + 32 + quad * 8];
      const int h0 = mt * 16 + quad * 4;
#pragma unroll
      for (int nt = 0; nt < 4; ++nt) {
        const int w = nt * 16 + col;
        const s16x8 bh0 = *(const s16x8*)&DtT_h[w * 64 + quad * 8];
        const s16x8 bl0 = *(const s16x8*)&DtT_l[w * 64 + quad * 8];
        const s16x8 bh1 = *(const s16x8*)&DtT_h[w * 64 + 32 + quad * 8];
        const s16x8 bl1 = *(const s16x8*)&DtT_l[w * 64 + 32 + quad * 8];
        f32x4 acc = zf;
        acc = MFMA16(a0, bh0, acc);
        acc = MFMA16(a0, bl0, acc);
        acc = MFMA16(a1, bh1, acc);
        acc = MFMA16(a1, bl1, acc);
        if (h0 < 56 && w < 56) {
#pragma unroll
          for (int r = 0; r < 4; ++r) yo[(h0 + r) * 56 + w] = f2bf(acc[r]);
        }
      }
    }
  }
}

// ---------------- 1x1 conv via MFMA, LDS-staged B + fused BN sums -----------
// Block: 128 pixels x 64 out-channels (oh 0..3). acc[4][2] = 32 VGPR.
// Per ks (32 in-channels): stage ybf[32c x 128p] -> LDS via coalesced dwordx4
// ([c][p] layout, stride 128 u16, p XOR-swizzled by ((c>>3)&3)<<3 at 8-pixel
// granularity); fragments read as 8 scalar u16 (~4-way conflicts, acceptable).
// Fragment values are bit-identical to the old direct-global path.
// Double-buffered, 1 barrier/ks, ks+1 prefetched in regs under MFMAs.
// BN sum/sq: shfl-reduce over 16 cols -> LDS atomics -> 1 global atomic/ch.
__global__ __launch_bounds__(256) void k_conv(const ushort_t* __restrict__ ybf,
                                              const ushort_t* __restrict__ W_h,
                                              const ushort_t* __restrict__ W_l,
                                              float* __restrict__ z,
                                              float* __restrict__ bnsum,
                                              float* __restrict__ bnsq) {
  __shared__ __align__(16) ushort_t tile[2][32 * 128];
  __shared__ float ls_sum[64];
  __shared__ float ls_sq[64];
  const int pb = blockIdx.x;   // 0..24, 128 pixels (last: 64 valid)
  const int oh = blockIdx.y;   // 0..3, 64 out-channels
  const int b  = blockIdx.z;
  const int tid = threadIdx.x;
  const int wave = tid >> 6, lane = tid & 63, col = lane & 15, quad = lane >> 4;
  const f32x4 zf = {0.f, 0.f, 0.f, 0.f};

  if (tid < 64) { ls_sum[tid] = 0.f; ls_sq[tid] = 0.f; }

  f32x4 acc[4][2];
#pragma unroll
  for (int mt = 0; mt < 4; ++mt)
#pragma unroll
    for (int i = 0; i < 2; ++i) acc[mt][i] = zf;

  const int p0 = pb * 128;
  int pL[2];
  bool act[2];
#pragma unroll
  for (int i = 0; i < 2; ++i) {
    pL[i] = (wave * 2 + i) * 16;
    act[i] = (p0 + pL[i]) < 3136;
  }
  int prd[2];  // swizzled LDS read index (pixel part)
#pragma unroll
  for (int i = 0; i < 2; ++i) prd[i] = (pL[i] + col) ^ (quad << 3);

  // staging: thread tid -> channel sc = tid>>3 (0..31), two 8-pixel chunks
  const int sc = tid >> 3;
  const int px8a = tid & 7;          // chunk 0..7  (pixels 0..63)
  const int px8b = (tid & 7) + 8;    // chunk 8..15 (pixels 64..127)
  const int swz = ((sc >> 3) & 3) << 3;
  const int lda = sc * 128 + ((px8a * 8) ^ swz);
  const int ldb = sc * 128 + ((px8b * 8) ^ swz);
  const bool sacta = (p0 + px8a * 8) < 3136;  // 3136 % 8 == 0: all-or-nothing
  const bool sactb = (p0 + px8b * 8) < 3136;

  const s16x8 zs = {0, 0, 0, 0, 0, 0, 0, 0};
  s16x8 pfa, pfb;
  {
    const size_t base = (size_t)(b * 256 + sc) * 3136 + p0;
    pfa = sacta ? *(const s16x8*)&ybf[base + px8a * 8] : zs;
    pfb = sactb ? *(const s16x8*)&ybf[base + px8b * 8] : zs;
  }

  int buf = 0;
  for (int ks = 0; ks < 8; ++ks) {
    *(s16x8*)&tile[buf][lda] = pfa;
    *(s16x8*)&tile[buf][ldb] = pfb;
    __syncthreads();
    if (ks < 7) {
      const size_t base = (size_t)(b * 256 + (ks + 1) * 32 + sc) * 3136 + p0;
      pfa = sacta ? *(const s16x8*)&ybf[base + px8a * 8] : zs;
      pfb = sactb ? *(const s16x8*)&ybf[base + px8b * 8] : zs;
    }
    s16x8 bfr[2];
#pragma unroll
    for (int i = 0; i < 2; ++i) {
      bfr[i] = zs;
      if (act[i]) {
#pragma unroll
        for (int j = 0; j < 8; ++j)
          bfr[i][j] = (short)tile[buf][(quad * 8 + j) * 128 + prd[i]];
      }
    }
#pragma unroll
    for (int mt = 0; mt < 4; ++mt) {
      const int orow = oh * 64 + mt * 16 + col;
      const s16x8 ah = *(const s16x8*)&W_h[orow * 256 + ks * 32 + quad * 8];
      const s16x8 al = *(const s16x8*)&W_l[orow * 256 + ks * 32 + quad * 8];
#pragma unroll
      for (int i = 0; i < 2; ++i) {
        if (act[i]) {
          acc[mt][i] = MFMA16(ah, bfr[i], acc[mt][i]);
          acc[mt][i] = MFMA16(al, bfr[i], acc[mt][i]);
        }
      }
    }
    buf ^= 1;
  }

  // epilogue: z stores + fused BN partial sums
#pragma unroll
  for (int mt = 0; mt < 4; ++mt) {
#pragma unroll
    for (int r = 0; r < 4; ++r) {
      const int chl = mt * 16 + quad * 4 + r;   // 0..63
      const int o = oh * 64 + chl;
      float s = 0.f, s2 = 0.f;
#pragma unroll
      for (int i = 0; i < 2; ++i) {
        if (act[i]) {
          const float v = acc[mt][i][r];
          s += v;
          s2 += v * v;
          z[((size_t)b * 256 + o) * 3136 + p0 + pL[i] + col] = v;
        }
      }
      s += __shfl_xor(s, 8, 16);
      s += __shfl_xor(s, 4, 16);
      s += __shfl_xor(s, 2, 16);
      s += __shfl_xor(s, 1, 16);
      s2 += __shfl_xor(s2, 8, 16);
      s2 += __shfl_xor(s2, 4, 16);
      s2 += __shfl_xor(s2, 2, 16);
      s2 += __shfl_xor(s2, 1, 16);
      if (col == 0) {
        atomicAdd(&ls_sum[chl], s);
        atomicAdd(&ls_sq[chl], s2);
      }
    }
  }
  __syncthreads();
  if (tid < 64) {
    atomicAdd(bnsum + oh * 64 + tid, ls_sum[tid]);
    atomicAdd(bnsq + oh * 64 + tid, ls_sq[tid]);
  }
}

__global__ void k_bnstats(const float* __restrict__ bnsum, const float* __restrict__ bnsq,
                          const float* __restrict__ bn_g, const float* __restrict__ bn_b,
                          float* __restrict__ scale, float* __restrict__ shift) {
  const int o = threadIdx.x;
  if (o < 256) {
    const float N = 32.f * 3136.f;
    const float m = bnsum[o] / N;
    const float v = bnsq[o] / N - m * m;
    const float sc = bn_g[o] / sqrtf(v + 1e-5f);
    scale[o] = sc;
    shift[o] = bn_b[o] - m * sc;
  }
}

__global__ __launch_bounds__(256) void k_bnapply(float* __restrict__ z,
                                                 const float* __restrict__ scale,
                                                 const float* __restrict__ shift) {
  const size_t i = ((size_t)blockIdx.x * 256 + threadIdx.x) * 4;
  const int ch = (int)((i / 3136) & 255);
  const float sc = scale[ch], sh = shift[ch];
  float4 v = *(float4*)(z + i);
  v.x = fmaf(v.x, sc, sh);
  v.y = fmaf(v.y, sc, sh);
  v.z = fmaf(v.z, sc, sh);
  v.w = fmaf(v.w, sc, sh);
  *(float4*)(z + i) = v;
}

extern "C" void kernel_launch(void* const* d_in, const int* in_sizes, int n_in,
                              void* d_out, int out_size, void* d_ws, size_t ws_size,
                              hipStream_t stream) {
  const float* x          = (const float*)d_in[0];
  const float* fc1_w      = (const float*)d_in[1];
  const float* fc1_b      = (const float*)d_in[2];
  const float* ln_g       = (const float*)d_in[3];
  const float* ln_b       = (const float*)d_in[4];
  const float* fh_w       = (const float*)d_in[5];
  const float* fh_b       = (const float*)d_in[6];
  const float* basis_real = (const float*)d_in[7];
  const float* basis_imag = (const float*)d_in[8];
  const float* conv_w     = (const float*)d_in[9];
  const float* bn_g       = (const float*)d_in[10];
  const float* bn_b       = (const float*)d_in[11];
  float* out = (float*)d_out;
  char* ws = (char*)d_ws;
  (void)in_sizes; (void)n_in; (void)out_size; (void)ws_size;

  float* ctx   = (float*)(ws + WO_CTX);
  float* hdn   = (float*)(ws + WO_HDN);
  float* bnsum = (float*)(ws + WO_BNSUM);
  float* bnsq  = (float*)(ws + WO_BNSQ);
  float* scale = (float*)(ws + WO_SCALE);
  float* shift = (float*)(ws + WO_SHIFT);
  float* coef  = (float*)(ws + WO_COEF);
  ushort_t* BmT_h  = (ushort_t*)(ws + WO_BMT_H);
  ushort_t* BmT_l  = (ushort_t*)(ws + WO_BMT_L);
  ushort_t* FARe_h = (ushort_t*)(ws + WO_FARE_H);
  ushort_t* FARe_l = (ushort_t*)(ws + WO_FARE_L);
  ushort_t* FAIm_h = (ushort_t*)(ws + WO_FAIM_H);
  ushort_t* FAIm_l = (ushort_t*)(ws + WO_FAIM_L);
  ushort_t* FDRe_h = (ushort_t*)(ws + WO_FDRE_H);
  ushort_t* FDRe_l = (ushort_t*)(ws + WO_FDRE_L);
  ushort_t* FDIm_h = (ushort_t*)(ws + WO_FDIM_H);
  ushort_t* FDIm_l = (ushort_t*)(ws + WO_FDIM_L);
  ushort_t* DtT_h  = (ushort_t*)(ws + WO_DTT_H);
  ushort_t* DtT_l  = (ushort_t*)(ws + WO_DTT_L);
  ushort_t* W_h    = (ushort_t*)(ws + WO_CW_H);
  ushort_t* W_l    = (ushort_t*)(ws + WO_CW_L);
  ushort_t* ybf    = (ushort_t*)(ws + WO_YBF);
  float* basRT = (float*)(ws + WO_BASRT);
  float* basIT = (float*)(ws + WO_BASIT);

  hipMemsetAsync(bnsum, 0, 2048, stream);  // bnsum+bnsq contiguous

  hipLaunchKernelGGL(k_const, dim3(528), dim3(256), 0, stream,
                     conv_w, basis_real, basis_imag,
                     BmT_h, BmT_l, FARe_h, FARe_l, FAIm_h, FAIm_l,
                     FDRe_h, FDRe_l, FDIm_h, FDIm_l, DtT_h, DtT_l, W_h, W_l,
                     basRT, basIT);
  hipLaunchKernelGGL(k_gap, dim3(8192), dim3(256), 0, stream, x, ctx);
  hipLaunchKernelGGL(k_mlp, dim3(32), dim3(64), 0, stream,
                     ctx, fc1_w, fc1_b, ln_g, ln_b, hdn);
  hipLaunchKernelGGL(k_coeffs, dim3(512), dim3(256), 0, stream, hdn, fh_w, fh_b, coef);
  hipLaunchKernelGGL(k_fft, dim3(8192), dim3(64), 0, stream,
                     x, coef, basRT, basIT,
                     BmT_h, BmT_l, FARe_h, FARe_l, FAIm_h, FAIm_l,
                     FDRe_h, FDRe_l, FDIm_h, FDIm_l, DtT_h, DtT_l, ybf);
  hipLaunchKernelGGL(k_conv, dim3(25, 4, 32), dim3(256), 0, stream,
                     ybf, W_h, W_l, out, bnsum, bnsq);
  hipLaunchKernelGGL(k_bnstats, dim3(1), dim3(256), 0, stream,
                     bnsum, bnsq, bn_g, bn_b, scale, shift);
  hipLaunchKernelGGL(k_bnapply, dim3(25088), dim3(256), 0, stream, out, scale, shift);
}